// Round 5
// baseline (1049.599 us; speedup 1.0000x reference)
//
#include <hip/hip_runtime.h>
#include <hip/hip_bf16.h>

// Problem constants
#define NTOK   32768          // 32 * 1024 tokens
#define BATCH  32
#define SEQ    1024
#define DIMD   768
#define HEADS  12
#define HDIM   64
#define MFEAT  384
#define HIDDEN 3072
#define SCALE  0.35355339059327379f   // 64^-0.25
#define HALF_SCALE2 0.0625f           // 0.5 * SCALE^2
#define EPSP   3.84e-6f               // 1e-8 / RSM^2 (RSM factors cancel in out)

typedef __attribute__((ext_vector_type(8))) short bf16x8;
typedef __attribute__((ext_vector_type(4))) float f32x4;

static __device__ __forceinline__ float bf2f(unsigned short u) {
    return __uint_as_float(((unsigned)u) << 16);
}
static __device__ __forceinline__ unsigned short f2bf(float f) {
    unsigned u = __float_as_uint(f);
    return (unsigned short)((u + 0x7FFFu + ((u >> 16) & 1u)) >> 16);  // RNE
}
static __device__ __forceinline__ float gelu_tanh(float v) {
    const float c = 0.7978845608028654f;
    float u = c * (v + 0.044715f * v * v * v);
    return 0.5f * v * (1.0f + tanhf(u));
}
static __device__ __forceinline__ void gload16(const void* g, void* l) {
    __builtin_amdgcn_global_load_lds(
        (const __attribute__((address_space(1))) void*)g,
        (__attribute__((address_space(3))) void*)l, 16, 0, 0);
}

// ---------------- fused LayerNorm -> bf16 (one block per 768-elem row) -----
__global__ __launch_bounds__(256) void ln_bf16(
    const float* __restrict__ x, const float* __restrict__ g,
    const float* __restrict__ bta, unsigned short* __restrict__ o) {
    const size_t row = blockIdx.x;
    const float* xr = x + row * DIMD;
    unsigned short* orow = o + row * DIMD;
    const int t = threadIdx.x;
    const float v0 = xr[t], v1 = xr[t + 256], v2 = xr[t + 512];
    float s  = v0 + v1 + v2;
    float sq = v0 * v0 + v1 * v1 + v2 * v2;
    const int lane = t & 63, w = t >> 6;
    #pragma unroll
    for (int off = 32; off > 0; off >>= 1) {
        s  += __shfl_down(s, off, 64);
        sq += __shfl_down(sq, off, 64);
    }
    __shared__ float red[2][4];
    if (lane == 0) { red[0][w] = s; red[1][w] = sq; }
    __syncthreads();
    s  = red[0][0] + red[0][1] + red[0][2] + red[0][3];
    sq = red[1][0] + red[1][1] + red[1][2] + red[1][3];
    const float mu  = s * (1.0f / DIMD);
    const float var = sq * (1.0f / DIMD) - mu * mu;
    const float r = rsqrtf(var + 1e-5f);
    orow[t]       = f2bf((v0 - mu) * r * g[t]       + bta[t]);
    orow[t + 256] = f2bf((v1 - mu) * r * g[t + 256] + bta[t + 256]);
    orow[t + 512] = f2bf((v2 - mu) * r * g[t + 512] + bta[t + 512]);
}

// ---------------- weight convert + transpose: W[K,N] f32 -> Wt[N,K] bf16 ---
__global__ __launch_bounds__(256) void wconv(
    const float* __restrict__ W, unsigned short* __restrict__ Wt, int K, int N) {
    __shared__ float tile[32][33];
    const int n0 = blockIdx.x << 5, k0 = blockIdx.y << 5;
    const int tn = threadIdx.x & 31, tg = threadIdx.x >> 5;   // tg 0..7
    #pragma unroll
    for (int i = 0; i < 4; ++i) {
        const int k = (tg << 2) + i;
        tile[k][tn] = W[(size_t)(k0 + k) * N + n0 + tn];
    }
    __syncthreads();
    #pragma unroll
    for (int i = 0; i < 4; ++i) {
        const int n = (tg << 2) + i;
        Wt[(size_t)(n0 + n) * K + k0 + tn] = f2bf(tile[tn][n]);
    }
}

// ---------------- worf prep: worf_ts[h][m][c] = bf16(SCALE * worf[h][c][m])
__global__ __launch_bounds__(256) void wprep(
    const float* __restrict__ worf, unsigned short* __restrict__ worf_ts) {
    __shared__ float tile[32][33];
    const int m0 = blockIdx.x << 5, c0 = blockIdx.y << 5, h = blockIdx.z;
    const int tn = threadIdx.x & 31, tg = threadIdx.x >> 5;
    #pragma unroll
    for (int i = 0; i < 4; ++i) {
        const int c = (tg << 2) + i;
        tile[c][tn] = worf[(size_t)(h * HDIM + c0 + c) * MFEAT + m0 + tn];
    }
    __syncthreads();
    #pragma unroll
    for (int i = 0; i < 4; ++i) {
        const int m = (tg << 2) + i;
        worf_ts[(size_t)(h * MFEAT + m0 + m) * HDIM + c0 + tn] =
            f2bf(SCALE * tile[tn][m]);
    }
}

// ---------------- bf16 MFMA GEMM: C = A[M,K] @ Wt[N,K]^T + bias ------------
// 128x128 tile, BK=32, 4 waves, wave 64x64. TRIPLE-buffered LDS staging with
// counted vmcnt (depth-2 latency hiding): tile t staged during iter t-2;
// steady-state wait = vmcnt(8) [2 younger tiles x 4 loads in flight],
// tail peels 4 -> 0.  Grid: blockIdx.x = row tile (fastest) so co-scheduled
// blocks share one 128-col W panel (L2-resident) instead of cycling all of W.
template <int ACT, bool RES, bool OBF16>
__global__ __launch_bounds__(256, 2) void gemm_mfma(
    const unsigned short* __restrict__ A, const unsigned short* __restrict__ Wt,
    const float* __restrict__ bias, const float* __restrict__ resid,
    void* __restrict__ Craw, int K, int N) {
    __shared__ unsigned short As[3][128 * 32];   // 8 KB per buffer
    __shared__ unsigned short Bs[3][128 * 32];
    const int t = threadIdx.x;
    const int w = t >> 6, l = t & 63;
    const int row0 = blockIdx.x << 7, col0 = blockIdx.y << 7;
    const int wr = (w >> 1) << 6, wc = (w & 1) << 6;

    const unsigned short* ag0 = A  + (size_t)(row0 + w * 32 + (l >> 2)) * K + ((l & 3) << 3);
    const unsigned short* ag1 = ag0 + (size_t)16 * K;
    const unsigned short* bg0 = Wt + (size_t)(col0 + w * 32 + (l >> 2)) * K + ((l & 3) << 3);
    const unsigned short* bg1 = bg0 + (size_t)16 * K;

    f32x4 acc[4][4] = {};
    const int NT = K >> 5;

    auto stage = [&](int bi, int s) {
        const size_t ko = (size_t)s << 5;   // 32 bf16 per K-step
        gload16(ag0 + ko, &As[bi][w * 1024]);
        gload16(ag1 + ko, &As[bi][w * 1024 + 512]);
        gload16(bg0 + ko, &Bs[bi][w * 1024]);
        gload16(bg1 + ko, &Bs[bi][w * 1024 + 512]);
    };

    stage(0, 0);
    stage(1, 1);
    const int lr = l & 15, lk = (l >> 4) << 3, lg = l >> 4;
    int c = 0;   // buffer holding tile s (tile t lives in buffer t%3)
    for (int s = 0; s < NT; ++s) {
        if (s + 2 < NT) stage((c + 2) % 3, s + 2);
        // wait for tile s's 4 loads (oldest); younger tiles stay in flight
        if (s + 2 < NT)      asm volatile("s_waitcnt vmcnt(8)" ::: "memory");
        else if (s + 1 < NT) asm volatile("s_waitcnt vmcnt(4)" ::: "memory");
        else                 asm volatile("s_waitcnt vmcnt(0)" ::: "memory");
        __builtin_amdgcn_s_barrier();            // all waves' tile-s writes visible
        __builtin_amdgcn_sched_barrier(0);       // no ds_read hoist above barrier
        const unsigned short* ab = &As[c][0];
        const unsigned short* bb = &Bs[c][0];
        bf16x8 af[4], bfr[4];
        #pragma unroll
        for (int f = 0; f < 4; ++f) {
            af[f]  = *(const bf16x8*)(ab + (wr + f * 16 + lr) * 32 + lk);
            bfr[f] = *(const bf16x8*)(bb + (wc + f * 16 + lr) * 32 + lk);
        }
        #pragma unroll
        for (int fi = 0; fi < 4; ++fi)
            #pragma unroll
            for (int fj = 0; fj < 4; ++fj)
                acc[fi][fj] = __builtin_amdgcn_mfma_f32_16x16x32_bf16(
                    af[fi], bfr[fj], acc[fi][fj], 0, 0, 0);
        __builtin_amdgcn_sched_barrier(0);       // reads complete before barrier
        __builtin_amdgcn_s_barrier();            // safe to restage this buffer
        c = (c + 1) == 3 ? 0 : c + 1;
    }

    float bv[4];
    #pragma unroll
    for (int fj = 0; fj < 4; ++fj) bv[fj] = bias[col0 + wc + fj * 16 + lr];
    #pragma unroll
    for (int fi = 0; fi < 4; ++fi) {
        #pragma unroll
        for (int r = 0; r < 4; ++r) {
            const int row = row0 + wr + fi * 16 + lg * 4 + r;
            const size_t base = (size_t)row * N + col0 + wc + lr;
            #pragma unroll
            for (int fj = 0; fj < 4; ++fj) {
                float v = acc[fi][fj][r] + bv[fj];
                if constexpr (RES) v += resid[base + fj * 16];
                if constexpr (ACT == 1) v = gelu_tanh(v);
                if constexpr (OBF16) ((unsigned short*)Craw)[base + fj * 16] = f2bf(v);
                else                 ((float*)Craw)[base + fj * 16] = v;
            }
        }
    }
}

// ---------------- Phase A (MFMA): per (b,h): ktvT[c][m] (+ksum row 64) -----
__global__ __launch_bounds__(256, 1) void ktv_mfma(
    const unsigned short* __restrict__ qkvb,
    const unsigned short* __restrict__ worf_ts,
    unsigned short* __restrict__ ktvT) {
    const int h = blockIdx.x, b = blockIdx.y, bh = b * HEADS + h;
    __shared__ __align__(16) unsigned short Klds[32][72];
    __shared__ __align__(16) unsigned short VT[80][40];
    __shared__ __align__(16) unsigned short P[4][96][40];
    const int t = threadIdx.x, w = t >> 6, l = t & 63;
    const int lr = l & 15, lg = l >> 4;
    const int m0 = w * 96;

    bf16x8 bfw[6][2];
    #pragma unroll
    for (int mt = 0; mt < 6; ++mt)
        #pragma unroll
        for (int ks = 0; ks < 2; ++ks)
            bfw[mt][ks] = *(const bf16x8*)(worf_ts +
                (size_t)(h * MFEAT + m0 + mt * 16 + lr) * HDIM + ks * 32 + lg * 8);

    f32x4 acc[5][6] = {};   // [c-tile][m-tile]

    for (int i = t; i < 16 * 40; i += 256) {
        const int r = 64 + i / 40, cc = i % 40;
        VT[r][cc] = (r == 64) ? (unsigned short)0x3F80 : (unsigned short)0;
    }
    const unsigned short* kglob = qkvb + (size_t)b * SEQ * 2304 + 768 + h * 64;
    const unsigned short* vglob = kglob + 768;

    for (int n0 = 0; n0 < SEQ; n0 += 32) {
        __syncthreads();
        {   // stage K tile [32][64]
            const int row = t >> 3, c8 = (t & 7) << 3;
            *(bf16x8*)&Klds[row][c8] =
                *(const bf16x8*)(kglob + (size_t)(n0 + row) * 2304 + c8);
        }
        {   // stage V^T tile [c][n]
            const int n = t & 31, c0 = (t >> 5) << 3;
            const unsigned short* src = vglob + (size_t)(n0 + n) * 2304 + c0;
            ushort4 v0 = *(const ushort4*)src;
            ushort4 v1 = *(const ushort4*)(src + 4);
            VT[c0 + 0][n] = v0.x; VT[c0 + 1][n] = v0.y;
            VT[c0 + 2][n] = v0.z; VT[c0 + 3][n] = v0.w;
            VT[c0 + 4][n] = v1.x; VT[c0 + 5][n] = v1.y;
            VT[c0 + 6][n] = v1.z; VT[c0 + 7][n] = v1.w;
        }
        __syncthreads();

        bf16x8 afk[2][2];
        float sqv[2][4];
        #pragma unroll
        for (int ns = 0; ns < 2; ++ns) {
            float s = 0.f;
            #pragma unroll
            for (int ks = 0; ks < 2; ++ks) {
                afk[ns][ks] = *(const bf16x8*)&Klds[ns * 16 + lr][ks * 32 + lg * 8];
                #pragma unroll
                for (int j = 0; j < 8; ++j) {
                    const float f = bf2f((unsigned short)afk[ns][ks][j]);
                    s += f * f;
                }
            }
            s += __shfl_xor(s, 16);
            s += __shfl_xor(s, 32);
            s *= HALF_SCALE2;
            #pragma unroll
            for (int r = 0; r < 4; ++r)
                sqv[ns][r] = __shfl(s, (lg << 2) + r);
        }

        #pragma unroll
        for (int mt = 0; mt < 6; ++mt) {
            #pragma unroll
            for (int ns = 0; ns < 2; ++ns) {
                f32x4 p = {};
                p = __builtin_amdgcn_mfma_f32_16x16x32_bf16(afk[ns][0], bfw[mt][0], p, 0, 0, 0);
                p = __builtin_amdgcn_mfma_f32_16x16x32_bf16(afk[ns][1], bfw[mt][1], p, 0, 0, 0);
                ushort4 pk;
                pk.x = f2bf(__expf(p[0] - sqv[ns][0]));
                pk.y = f2bf(__expf(p[1] - sqv[ns][1]));
                pk.z = f2bf(__expf(p[2] - sqv[ns][2]));
                pk.w = f2bf(__expf(p[3] - sqv[ns][3]));
                *(ushort4*)&P[w][mt * 16 + lr][ns * 16 + lg * 4] = pk;
            }
        }
        asm volatile("s_waitcnt lgkmcnt(0)" ::: "memory");
        __builtin_amdgcn_sched_barrier(0);

        bf16x8 afv[5];
        #pragma unroll
        for (int ct = 0; ct < 5; ++ct)
            afv[ct] = *(const bf16x8*)&VT[ct * 16 + lr][lg * 8];
        #pragma unroll
        for (int mt = 0; mt < 6; ++mt) {
            const bf16x8 bp = *(const bf16x8*)&P[w][mt * 16 + lr][lg * 8];
            #pragma unroll
            for (int ct = 0; ct < 5; ++ct)
                acc[ct][mt] = __builtin_amdgcn_mfma_f32_16x16x32_bf16(afv[ct], bp, acc[ct][mt], 0, 0, 0);
        }
    }

    unsigned short* dst = ktvT + (size_t)bh * 80 * MFEAT;
    #pragma unroll
    for (int ct = 0; ct < 5; ++ct)
        #pragma unroll
        for (int mt = 0; mt < 6; ++mt)
            #pragma unroll
            for (int r = 0; r < 4; ++r) {
                const int cc = ct * 16 + lg * 4 + r;
                const int m = m0 + mt * 16 + lr;
                dst[(size_t)cc * MFEAT + m] = f2bf(acc[ct][mt][r]);
            }
}

// ---------------- Phase B (MFMA): out^T[c,n] = sum_m ktvT[c,m] * phi_q[n,m]
__global__ __launch_bounds__(256) void attn_out_mfma(
    const unsigned short* __restrict__ qkvb,
    const unsigned short* __restrict__ worf_ts,
    const unsigned short* __restrict__ ktvT,
    unsigned short* __restrict__ attn) {
    const int n0 = blockIdx.x << 7;
    const int h = blockIdx.y, b = blockIdx.z, bh = b * HEADS + h;
    __shared__ __align__(16) unsigned short KT[80][104];
    __shared__ __align__(16) unsigned short P[4][32][104];
    const int t = threadIdx.x, w = t >> 6, l = t & 63;
    const int lr = l & 15, lg = l >> 4;
    const int nw = n0 + w * 32;

    bf16x8 bq[2][2];
    float sqn[2];
    #pragma unroll
    for (int nt = 0; nt < 2; ++nt) {
        float s = 0.f;
        #pragma unroll
        for (int ks = 0; ks < 2; ++ks) {
            bq[nt][ks] = *(const bf16x8*)(qkvb +
                (size_t)(b * SEQ + nw + nt * 16 + lr) * 2304 + h * 64 + ks * 32 + lg * 8);
            #pragma unroll
            for (int j = 0; j < 8; ++j) {
                const float f = bf2f((unsigned short)bq[nt][ks][j]);
                s += f * f;
            }
        }
        s += __shfl_xor(s, 16);
        s += __shfl_xor(s, 32);
        sqn[nt] = s * HALF_SCALE2;
    }

    f32x4 acc[5][2] = {};
    const unsigned short* ktg = ktvT + (size_t)bh * 80 * MFEAT;

    for (int ch = 0; ch < 4; ++ch) {
        const int m0 = ch * 96;
        __syncthreads();
        for (int i = t; i < 1920; i += 256) {
            const int row = i / 24, q = i % 24;
            *(ushort4*)&KT[row][q * 4] =
                *(const ushort4*)(ktg + (size_t)row * MFEAT + m0 + q * 4);
        }
        __syncthreads();

        #pragma unroll
        for (int mt = 0; mt < 6; ++mt) {
            bf16x8 afw[2];
            #pragma unroll
            for (int ks = 0; ks < 2; ++ks)
                afw[ks] = *(const bf16x8*)(worf_ts +
                    (size_t)(h * MFEAT + m0 + mt * 16 + lr) * HDIM + ks * 32 + lg * 8);
            #pragma unroll
            for (int nt = 0; nt < 2; ++nt) {
                f32x4 p = {};
                p = __builtin_amdgcn_mfma_f32_16x16x32_bf16(afw[0], bq[nt][0], p, 0, 0, 0);
                p = __builtin_amdgcn_mfma_f32_16x16x32_bf16(afw[1], bq[nt][1], p, 0, 0, 0);
                ushort4 pk;
                pk.x = f2bf(__expf(p[0] - sqn[nt]));
                pk.y = f2bf(__expf(p[1] - sqn[nt]));
                pk.z = f2bf(__expf(p[2] - sqn[nt]));
                pk.w = f2bf(__expf(p[3] - sqn[nt]));
                *(ushort4*)&P[w][nt * 16 + lr][mt * 16 + lg * 4] = pk;
            }
        }
        asm volatile("s_waitcnt lgkmcnt(0)" ::: "memory");
        __builtin_amdgcn_sched_barrier(0);

        #pragma unroll
        for (int ks = 0; ks < 3; ++ks) {
            bf16x8 bp[2];
            #pragma unroll
            for (int nt = 0; nt < 2; ++nt)
                bp[nt] = *(const bf16x8*)&P[w][nt * 16 + lr][ks * 32 + lg * 8];
            #pragma unroll
            for (int ct = 0; ct < 5; ++ct) {
                const bf16x8 av = *(const bf16x8*)&KT[ct * 16 + lr][ks * 32 + lg * 8];
                #pragma unroll
                for (int nt = 0; nt < 2; ++nt)
                    acc[ct][nt] = __builtin_amdgcn_mfma_f32_16x16x32_bf16(av, bp[nt], acc[ct][nt], 0, 0, 0);
            }
        }
    }

    #pragma unroll
    for (int nt = 0; nt < 2; ++nt) {
        const float d = __shfl(acc[4][nt][0], lr);
        const float inv = 1.0f / (d + EPSP);
        const int token = b * SEQ + nw + nt * 16 + lr;
        #pragma unroll
        for (int ct = 0; ct < 4; ++ct)
            #pragma unroll
            for (int r = 0; r < 4; ++r) {
                const int cc = ct * 16 + lg * 4 + r;
                attn[(size_t)token * DIMD + h * 64 + cc] = f2bf(acc[ct][nt][r] * inv);
            }
    }
}

// ---------------------------------------------------------------------------
extern "C" void kernel_launch(void* const* d_in, const int* in_sizes, int n_in,
                              void* d_out, int out_size, void* d_ws, size_t ws_size,
                              hipStream_t stream) {
    const float* x      = (const float*)d_in[0];
    const float* ln1_g  = (const float*)d_in[1];
    const float* ln1_b  = (const float*)d_in[2];
    const float* qkv_w  = (const float*)d_in[3];
    const float* qkv_b  = (const float*)d_in[4];
    const float* w_orf  = (const float*)d_in[5];
    const float* proj_w = (const float*)d_in[6];
    const float* proj_b = (const float*)d_in[7];
    const float* ln2_g  = (const float*)d_in[8];
    const float* ln2_b  = (const float*)d_in[9];
    const float* fc1_w  = (const float*)d_in[10];
    const float* fc1_b  = (const float*)d_in[11];
    const float* fc2_w  = (const float*)d_in[12];
    const float* fc2_b  = (const float*)d_in[13];
    float* out = (float*)d_out;

    // Workspace layout (bytes), total 265,814,016 B (= round-3 proven size).
    char* wsb = (char*)d_ws;
    unsigned short* qkvb    = (unsigned short*)wsb;                  // bf16 T*2304 [0, 150994944)
    unsigned short* attn    = (unsigned short*)(wsb + 150994944);    // bf16 T*768  [.., 201326592)
    unsigned short* ktvT    = (unsigned short*)(wsb + 201326592);    // bf16 384*80*384 = 23,592,960
    unsigned short* worf_ts = (unsigned short*)(wsb + 224919552);    // bf16 12*384*64 = 589,824
    unsigned short* y2      = (unsigned short*)(wsb + 201326592);    // LN2 out (ktvT/worf_ts dead)
    unsigned short* hid     = qkvb;                                  // bf16 T*3072 aliases qkvb+attn
    unsigned short* qkv_wt  = (unsigned short*)(wsb + 251658240);    // [2304,768]  3,538,944
    unsigned short* proj_wt = (unsigned short*)(wsb + 255197184);    // [768,768]   1,179,648
    unsigned short* fc1_wt  = (unsigned short*)(wsb + 256376832);    // [3072,768]  4,718,592
    unsigned short* fc2_wt  = (unsigned short*)(wsb + 261095424);    // [768,3072]  4,718,592
    unsigned short* xln     = (unsigned short*)d_out;                // bf16 T*768 in d_out (free until step 5)

    // 0) weight prep
    wconv<<<dim3(2304 / 32, 768 / 32), 256, 0, stream>>>(qkv_w, qkv_wt, DIMD, 2304);
    wconv<<<dim3(768 / 32, 768 / 32), 256, 0, stream>>>(proj_w, proj_wt, DIMD, DIMD);
    wconv<<<dim3(3072 / 32, 768 / 32), 256, 0, stream>>>(fc1_w, fc1_wt, DIMD, HIDDEN);
    wconv<<<dim3(768 / 32, 3072 / 32), 256, 0, stream>>>(fc2_w, fc2_wt, HIDDEN, DIMD);
    wprep<<<dim3(MFEAT / 32, HDIM / 32, HEADS), 256, 0, stream>>>(w_orf, worf_ts);
    // 1) xln = LN1(x) (bf16, in d_out)
    ln_bf16<<<NTOK, 256, 0, stream>>>(x, ln1_g, ln1_b, xln);
    // 2) qkv = xln @ qkv_w + qkv_b (bf16)   grid: rows fastest
    gemm_mfma<0, false, true><<<dim3(NTOK / 128, 2304 / 128), 256, 0, stream>>>(
        xln, qkv_wt, qkv_b, nullptr, qkvb, DIMD, 2304);
    // 3) phase A: ktvT (incl. ksum row)
    ktv_mfma<<<dim3(HEADS, BATCH), 256, 0, stream>>>(qkvb, worf_ts, ktvT);
    // 4) phase B: attn out (bf16)
    attn_out_mfma<<<dim3(SEQ / 128, HEADS, BATCH), 256, 0, stream>>>(
        qkvb, worf_ts, ktvT, attn);
    // 5) h = x + attn @ proj_w + proj_b -> d_out (f32)
    gemm_mfma<0, true, false><<<dim3(NTOK / 128, DIMD / 128), 256, 0, stream>>>(
        attn, proj_wt, proj_b, x, out, DIMD, DIMD);
    // 6) y2 = LN2(h) (bf16)
    ln_bf16<<<NTOK, 256, 0, stream>>>(out, ln2_g, ln2_b, y2);
    // 7) hid = gelu(y2 @ fc1_w + fc1_b) (bf16)
    gemm_mfma<1, false, true><<<dim3(NTOK / 128, HIDDEN / 128), 256, 0, stream>>>(
        y2, fc1_wt, fc1_b, nullptr, hid, DIMD, HIDDEN);
    // 8) out = h + hid @ fc2_w + fc2_b (in-place residual on d_out)
    gemm_mfma<0, true, false><<<dim3(NTOK / 128, DIMD / 128), 256, 0, stream>>>(
        hid, fc2_wt, fc2_b, out, out, HIDDEN, DIMD);
}

// Round 6
// 1032.738 us; speedup vs baseline: 1.0163x; 1.0163x over previous
//
#include <hip/hip_runtime.h>
#include <hip/hip_bf16.h>

// Problem constants
#define NTOK   32768          // 32 * 1024 tokens
#define BATCH  32
#define SEQ    1024
#define DIMD   768
#define HEADS  12
#define HDIM   64
#define MFEAT  384
#define HIDDEN 3072
#define SCALE  0.35355339059327379f   // 64^-0.25
#define HALF_SCALE2 0.0625f           // 0.5 * SCALE^2
#define EPSP   3.84e-6f               // 1e-8 / RSM^2 (RSM factors cancel in out)

typedef __attribute__((ext_vector_type(8))) short bf16x8;
typedef __attribute__((ext_vector_type(4))) float f32x4;

static __device__ __forceinline__ float bf2f(unsigned short u) {
    return __uint_as_float(((unsigned)u) << 16);
}
static __device__ __forceinline__ unsigned short f2bf(float f) {
    unsigned u = __float_as_uint(f);
    return (unsigned short)((u + 0x7FFFu + ((u >> 16) & 1u)) >> 16);  // RNE
}
// gelu tanh-approx, exp form: 0.5v(1+tanh(u)) == v / (1 + e^{-2u}), u = c(v+0.044715v^3)
// overflow-safe: u->+inf => e^-2u->0 => v; u->-inf => e^-2u->inf => 0.
static __device__ __forceinline__ float gelu_fast(float v) {
    const float c = 0.7978845608028654f;
    const float u = c * v * (1.0f + 0.044715f * v * v);
    return v / (1.0f + __expf(-2.0f * u));
}
static __device__ __forceinline__ void gload16(const void* g, void* l) {
    __builtin_amdgcn_global_load_lds(
        (const __attribute__((address_space(1))) void*)g,
        (__attribute__((address_space(3))) void*)l, 16, 0, 0);
}

// ---------------- fused LayerNorm -> bf16 (one block per 768-elem row) -----
__global__ __launch_bounds__(256) void ln_bf16(
    const float* __restrict__ x, const float* __restrict__ g,
    const float* __restrict__ bta, unsigned short* __restrict__ o) {
    const size_t row = blockIdx.x;
    const float* xr = x + row * DIMD;
    unsigned short* orow = o + row * DIMD;
    const int t = threadIdx.x;
    const float v0 = xr[t], v1 = xr[t + 256], v2 = xr[t + 512];
    float s  = v0 + v1 + v2;
    float sq = v0 * v0 + v1 * v1 + v2 * v2;
    const int lane = t & 63, w = t >> 6;
    #pragma unroll
    for (int off = 32; off > 0; off >>= 1) {
        s  += __shfl_down(s, off, 64);
        sq += __shfl_down(sq, off, 64);
    }
    __shared__ float red[2][4];
    if (lane == 0) { red[0][w] = s; red[1][w] = sq; }
    __syncthreads();
    s  = red[0][0] + red[0][1] + red[0][2] + red[0][3];
    sq = red[1][0] + red[1][1] + red[1][2] + red[1][3];
    const float mu  = s * (1.0f / DIMD);
    const float var = sq * (1.0f / DIMD) - mu * mu;
    const float r = rsqrtf(var + 1e-5f);
    orow[t]       = f2bf((v0 - mu) * r * g[t]       + bta[t]);
    orow[t + 256] = f2bf((v1 - mu) * r * g[t + 256] + bta[t + 256]);
    orow[t + 512] = f2bf((v2 - mu) * r * g[t + 512] + bta[t + 512]);
}

// ---------------- weight convert + transpose: W[K,N] f32 -> Wt[N,K] bf16 ---
__global__ __launch_bounds__(256) void wconv(
    const float* __restrict__ W, unsigned short* __restrict__ Wt, int K, int N) {
    __shared__ float tile[32][33];
    const int n0 = blockIdx.x << 5, k0 = blockIdx.y << 5;
    const int tn = threadIdx.x & 31, tg = threadIdx.x >> 5;   // tg 0..7
    #pragma unroll
    for (int i = 0; i < 4; ++i) {
        const int k = (tg << 2) + i;
        tile[k][tn] = W[(size_t)(k0 + k) * N + n0 + tn];
    }
    __syncthreads();
    #pragma unroll
    for (int i = 0; i < 4; ++i) {
        const int n = (tg << 2) + i;
        Wt[(size_t)(n0 + n) * K + k0 + tn] = f2bf(tile[tn][n]);
    }
}

// ---------------- worf prep: worf_ts[h][m][c] = bf16(SCALE * worf[h][c][m])
__global__ __launch_bounds__(256) void wprep(
    const float* __restrict__ worf, unsigned short* __restrict__ worf_ts) {
    __shared__ float tile[32][33];
    const int m0 = blockIdx.x << 5, c0 = blockIdx.y << 5, h = blockIdx.z;
    const int tn = threadIdx.x & 31, tg = threadIdx.x >> 5;
    #pragma unroll
    for (int i = 0; i < 4; ++i) {
        const int c = (tg << 2) + i;
        tile[c][tn] = worf[(size_t)(h * HDIM + c0 + c) * MFEAT + m0 + tn];
    }
    __syncthreads();
    #pragma unroll
    for (int i = 0; i < 4; ++i) {
        const int m = (tg << 2) + i;
        worf_ts[(size_t)(h * MFEAT + m0 + m) * HDIM + c0 + tn] =
            f2bf(SCALE * tile[tn][m]);
    }
}

// ---------------- bf16 MFMA GEMM: C = A[M,K] @ Wt[N,K]^T + bias ------------
// 128x128 tile, BK=32, 256 threads (4 waves), wave owns 64x64 (4x4 frags of
// 16x16x32 MFMA). Double-buffered LDS, global_load_lds width-16 staging.
// C stores are nontemporal (write stream must not evict A/W from L2/L3).
template <int ACT, bool RES, bool OBF16>
__global__ __launch_bounds__(256, 2) void gemm_mfma(
    const unsigned short* __restrict__ A, const unsigned short* __restrict__ Wt,
    const float* __restrict__ bias, const float* __restrict__ resid,
    void* __restrict__ Craw, int K, int N) {
    __shared__ unsigned short As[2][128 * 32];   // 8 KB per buffer
    __shared__ unsigned short Bs[2][128 * 32];
    const int t = threadIdx.x;
    const int w = t >> 6, l = t & 63;
    const int row0 = blockIdx.y << 7, col0 = blockIdx.x << 7;
    const int wr = (w >> 1) << 6, wc = (w & 1) << 6;

    const unsigned short* ag0 = A  + (size_t)(row0 + w * 32 + (l >> 2)) * K + ((l & 3) << 3);
    const unsigned short* ag1 = ag0 + (size_t)16 * K;
    const unsigned short* bg0 = Wt + (size_t)(col0 + w * 32 + (l >> 2)) * K + ((l & 3) << 3);
    const unsigned short* bg1 = bg0 + (size_t)16 * K;

    f32x4 acc[4][4] = {};
    const int NT = K >> 5;

    auto stage = [&](int bi, int s) {
        const size_t ko = (size_t)s << 5;   // 32 bf16 per K-step
        gload16(ag0 + ko, &As[bi][w * 1024]);
        gload16(ag1 + ko, &As[bi][w * 1024 + 512]);
        gload16(bg0 + ko, &Bs[bi][w * 1024]);
        gload16(bg1 + ko, &Bs[bi][w * 1024 + 512]);
    };

    stage(0, 0);
    const int lr = l & 15, lk = (l >> 4) << 3, lg = l >> 4;
    for (int s = 0; s < NT; ++s) {
        __syncthreads();                       // buf[s&1] staged; prior reads of buf[(s+1)&1] done
        if (s + 1 < NT) stage((s + 1) & 1, s + 1);
        const unsigned short* ab = &As[s & 1][0];
        const unsigned short* bb = &Bs[s & 1][0];
        bf16x8 af[4], bfr[4];
        #pragma unroll
        for (int f = 0; f < 4; ++f) {
            af[f]  = *(const bf16x8*)(ab + (wr + f * 16 + lr) * 32 + lk);
            bfr[f] = *(const bf16x8*)(bb + (wc + f * 16 + lr) * 32 + lk);
        }
        #pragma unroll
        for (int fi = 0; fi < 4; ++fi)
            #pragma unroll
            for (int fj = 0; fj < 4; ++fj)
                acc[fi][fj] = __builtin_amdgcn_mfma_f32_16x16x32_bf16(
                    af[fi], bfr[fj], acc[fi][fj], 0, 0, 0);
    }

    float bv[4];
    #pragma unroll
    for (int fj = 0; fj < 4; ++fj) bv[fj] = bias[col0 + wc + fj * 16 + lr];
    #pragma unroll
    for (int fi = 0; fi < 4; ++fi) {
        #pragma unroll
        for (int r = 0; r < 4; ++r) {
            const int row = row0 + wr + fi * 16 + lg * 4 + r;
            const size_t base = (size_t)row * N + col0 + wc + lr;
            #pragma unroll
            for (int fj = 0; fj < 4; ++fj) {
                float v = acc[fi][fj][r] + bv[fj];
                if constexpr (RES) v += __builtin_nontemporal_load(&resid[base + fj * 16]);
                if constexpr (ACT == 1) v = gelu_fast(v);
                if constexpr (OBF16)
                    __builtin_nontemporal_store(f2bf(v), &((unsigned short*)Craw)[base + fj * 16]);
                else
                    __builtin_nontemporal_store(v, &((float*)Craw)[base + fj * 16]);
            }
        }
    }
}

// ---------------- Phase A (MFMA): per (b,h): ktvT[c][m] (+ksum row 64) -----
__global__ __launch_bounds__(256, 1) void ktv_mfma(
    const unsigned short* __restrict__ qkvb,
    const unsigned short* __restrict__ worf_ts,
    unsigned short* __restrict__ ktvT) {
    const int h = blockIdx.x, b = blockIdx.y, bh = b * HEADS + h;
    __shared__ __align__(16) unsigned short Klds[32][72];
    __shared__ __align__(16) unsigned short VT[80][40];
    __shared__ __align__(16) unsigned short P[4][96][40];
    const int t = threadIdx.x, w = t >> 6, l = t & 63;
    const int lr = l & 15, lg = l >> 4;
    const int m0 = w * 96;

    bf16x8 bfw[6][2];
    #pragma unroll
    for (int mt = 0; mt < 6; ++mt)
        #pragma unroll
        for (int ks = 0; ks < 2; ++ks)
            bfw[mt][ks] = *(const bf16x8*)(worf_ts +
                (size_t)(h * MFEAT + m0 + mt * 16 + lr) * HDIM + ks * 32 + lg * 8);

    f32x4 acc[5][6] = {};   // [c-tile][m-tile]

    for (int i = t; i < 16 * 40; i += 256) {
        const int r = 64 + i / 40, cc = i % 40;
        VT[r][cc] = (r == 64) ? (unsigned short)0x3F80 : (unsigned short)0;
    }
    const unsigned short* kglob = qkvb + (size_t)b * SEQ * 2304 + 768 + h * 64;
    const unsigned short* vglob = kglob + 768;

    for (int n0 = 0; n0 < SEQ; n0 += 32) {
        __syncthreads();
        {   // stage K tile [32][64]
            const int row = t >> 3, c8 = (t & 7) << 3;
            *(bf16x8*)&Klds[row][c8] =
                *(const bf16x8*)(kglob + (size_t)(n0 + row) * 2304 + c8);
        }
        {   // stage V^T tile [c][n]
            const int n = t & 31, c0 = (t >> 5) << 3;
            const unsigned short* src = vglob + (size_t)(n0 + n) * 2304 + c0;
            ushort4 v0 = *(const ushort4*)src;
            ushort4 v1 = *(const ushort4*)(src + 4);
            VT[c0 + 0][n] = v0.x; VT[c0 + 1][n] = v0.y;
            VT[c0 + 2][n] = v0.z; VT[c0 + 3][n] = v0.w;
            VT[c0 + 4][n] = v1.x; VT[c0 + 5][n] = v1.y;
            VT[c0 + 6][n] = v1.z; VT[c0 + 7][n] = v1.w;
        }
        __syncthreads();

        bf16x8 afk[2][2];
        float sqv[2][4];
        #pragma unroll
        for (int ns = 0; ns < 2; ++ns) {
            float s = 0.f;
            #pragma unroll
            for (int ks = 0; ks < 2; ++ks) {
                afk[ns][ks] = *(const bf16x8*)&Klds[ns * 16 + lr][ks * 32 + lg * 8];
                #pragma unroll
                for (int j = 0; j < 8; ++j) {
                    const float f = bf2f((unsigned short)afk[ns][ks][j]);
                    s += f * f;
                }
            }
            s += __shfl_xor(s, 16);
            s += __shfl_xor(s, 32);
            s *= HALF_SCALE2;
            #pragma unroll
            for (int r = 0; r < 4; ++r)
                sqv[ns][r] = __shfl(s, (lg << 2) + r);
        }

        #pragma unroll
        for (int mt = 0; mt < 6; ++mt) {
            #pragma unroll
            for (int ns = 0; ns < 2; ++ns) {
                f32x4 p = {};
                p = __builtin_amdgcn_mfma_f32_16x16x32_bf16(afk[ns][0], bfw[mt][0], p, 0, 0, 0);
                p = __builtin_amdgcn_mfma_f32_16x16x32_bf16(afk[ns][1], bfw[mt][1], p, 0, 0, 0);
                ushort4 pk;
                pk.x = f2bf(__expf(p[0] - sqv[ns][0]));
                pk.y = f2bf(__expf(p[1] - sqv[ns][1]));
                pk.z = f2bf(__expf(p[2] - sqv[ns][2]));
                pk.w = f2bf(__expf(p[3] - sqv[ns][3]));
                *(ushort4*)&P[w][mt * 16 + lr][ns * 16 + lg * 4] = pk;
            }
        }
        asm volatile("s_waitcnt lgkmcnt(0)" ::: "memory");
        __builtin_amdgcn_sched_barrier(0);

        bf16x8 afv[5];
        #pragma unroll
        for (int ct = 0; ct < 5; ++ct)
            afv[ct] = *(const bf16x8*)&VT[ct * 16 + lr][lg * 8];
        #pragma unroll
        for (int mt = 0; mt < 6; ++mt) {
            const bf16x8 bp = *(const bf16x8*)&P[w][mt * 16 + lr][lg * 8];
            #pragma unroll
            for (int ct = 0; ct < 5; ++ct)
                acc[ct][mt] = __builtin_amdgcn_mfma_f32_16x16x32_bf16(afv[ct], bp, acc[ct][mt], 0, 0, 0);
        }
    }

    unsigned short* dst = ktvT + (size_t)bh * 80 * MFEAT;
    #pragma unroll
    for (int ct = 0; ct < 5; ++ct)
        #pragma unroll
        for (int mt = 0; mt < 6; ++mt)
            #pragma unroll
            for (int r = 0; r < 4; ++r) {
                const int cc = ct * 16 + lg * 4 + r;
                const int m = m0 + mt * 16 + lr;
                dst[(size_t)cc * MFEAT + m] = f2bf(acc[ct][mt][r]);
            }
}

// ---------------- Phase B (MFMA): out^T[c,n] = sum_m ktvT[c,m] * phi_q[n,m]
__global__ __launch_bounds__(256) void attn_out_mfma(
    const unsigned short* __restrict__ qkvb,
    const unsigned short* __restrict__ worf_ts,
    const unsigned short* __restrict__ ktvT,
    unsigned short* __restrict__ attn) {
    const int n0 = blockIdx.x << 7;
    const int h = blockIdx.y, b = blockIdx.z, bh = b * HEADS + h;
    __shared__ __align__(16) unsigned short KT[80][104];
    __shared__ __align__(16) unsigned short P[4][32][104];
    const int t = threadIdx.x, w = t >> 6, l = t & 63;
    const int lr = l & 15, lg = l >> 4;
    const int nw = n0 + w * 32;

    bf16x8 bq[2][2];
    float sqn[2];
    #pragma unroll
    for (int nt = 0; nt < 2; ++nt) {
        float s = 0.f;
        #pragma unroll
        for (int ks = 0; ks < 2; ++ks) {
            bq[nt][ks] = *(const bf16x8*)(qkvb +
                (size_t)(b * SEQ + nw + nt * 16 + lr) * 2304 + h * 64 + ks * 32 + lg * 8);
            #pragma unroll
            for (int j = 0; j < 8; ++j) {
                const float f = bf2f((unsigned short)bq[nt][ks][j]);
                s += f * f;
            }
        }
        s += __shfl_xor(s, 16);
        s += __shfl_xor(s, 32);
        sqn[nt] = s * HALF_SCALE2;
    }

    f32x4 acc[5][2] = {};
    const unsigned short* ktg = ktvT + (size_t)bh * 80 * MFEAT;

    for (int ch = 0; ch < 4; ++ch) {
        const int m0 = ch * 96;
        __syncthreads();
        for (int i = t; i < 1920; i += 256) {
            const int row = i / 24, q = i % 24;
            *(ushort4*)&KT[row][q * 4] =
                *(const ushort4*)(ktg + (size_t)row * MFEAT + m0 + q * 4);
        }
        __syncthreads();

        #pragma unroll
        for (int mt = 0; mt < 6; ++mt) {
            bf16x8 afw[2];
            #pragma unroll
            for (int ks = 0; ks < 2; ++ks)
                afw[ks] = *(const bf16x8*)(worf_ts +
                    (size_t)(h * MFEAT + m0 + mt * 16 + lr) * HDIM + ks * 32 + lg * 8);
            #pragma unroll
            for (int nt = 0; nt < 2; ++nt) {
                f32x4 p = {};
                p = __builtin_amdgcn_mfma_f32_16x16x32_bf16(afw[0], bq[nt][0], p, 0, 0, 0);
                p = __builtin_amdgcn_mfma_f32_16x16x32_bf16(afw[1], bq[nt][1], p, 0, 0, 0);
                ushort4 pk;
                pk.x = f2bf(__expf(p[0] - sqn[nt]));
                pk.y = f2bf(__expf(p[1] - sqn[nt]));
                pk.z = f2bf(__expf(p[2] - sqn[nt]));
                pk.w = f2bf(__expf(p[3] - sqn[nt]));
                *(ushort4*)&P[w][nt * 16 + lr][mt * 16 + lg * 4] = pk;
            }
        }
        asm volatile("s_waitcnt lgkmcnt(0)" ::: "memory");
        __builtin_amdgcn_sched_barrier(0);

        #pragma unroll
        for (int ks = 0; ks < 3; ++ks) {
            bf16x8 bp[2];
            #pragma unroll
            for (int nt = 0; nt < 2; ++nt)
                bp[nt] = *(const bf16x8*)&P[w][nt * 16 + lr][ks * 32 + lg * 8];
            #pragma unroll
            for (int ct = 0; ct < 5; ++ct) {
                const bf16x8 av = *(const bf16x8*)&KT[ct * 16 + lr][ks * 32 + lg * 8];
                #pragma unroll
                for (int nt = 0; nt < 2; ++nt)
                    acc[ct][nt] = __builtin_amdgcn_mfma_f32_16x16x32_bf16(av, bp[nt], acc[ct][nt], 0, 0, 0);
            }
        }
    }

    #pragma unroll
    for (int nt = 0; nt < 2; ++nt) {
        const float d = __shfl(acc[4][nt][0], lr);
        const float inv = 1.0f / (d + EPSP);
        const int token = b * SEQ + nw + nt * 16 + lr;
        #pragma unroll
        for (int ct = 0; ct < 4; ++ct)
            #pragma unroll
            for (int r = 0; r < 4; ++r) {
                const int cc = ct * 16 + lg * 4 + r;
                attn[(size_t)token * DIMD + h * 64 + cc] = f2bf(acc[ct][nt][r] * inv);
            }
    }
}

// ---------------------------------------------------------------------------
extern "C" void kernel_launch(void* const* d_in, const int* in_sizes, int n_in,
                              void* d_out, int out_size, void* d_ws, size_t ws_size,
                              hipStream_t stream) {
    const float* x      = (const float*)d_in[0];
    const float* ln1_g  = (const float*)d_in[1];
    const float* ln1_b  = (const float*)d_in[2];
    const float* qkv_w  = (const float*)d_in[3];
    const float* qkv_b  = (const float*)d_in[4];
    const float* w_orf  = (const float*)d_in[5];
    const float* proj_w = (const float*)d_in[6];
    const float* proj_b = (const float*)d_in[7];
    const float* ln2_g  = (const float*)d_in[8];
    const float* ln2_b  = (const float*)d_in[9];
    const float* fc1_w  = (const float*)d_in[10];
    const float* fc1_b  = (const float*)d_in[11];
    const float* fc2_w  = (const float*)d_in[12];
    const float* fc2_b  = (const float*)d_in[13];
    float* out = (float*)d_out;

    // Workspace layout (bytes), total 265,814,016 B (= round-3 proven size).
    char* wsb = (char*)d_ws;
    unsigned short* qkvb    = (unsigned short*)wsb;                  // bf16 T*2304 [0, 150994944)
    unsigned short* attn    = (unsigned short*)(wsb + 150994944);    // bf16 T*768  [.., 201326592)
    unsigned short* ktvT    = (unsigned short*)(wsb + 201326592);    // bf16 384*80*384 = 23,592,960
    unsigned short* worf_ts = (unsigned short*)(wsb + 224919552);    // bf16 12*384*64 = 589,824
    unsigned short* y2      = (unsigned short*)(wsb + 201326592);    // LN2 out (ktvT/worf_ts dead)
    unsigned short* hid     = qkvb;                                  // bf16 T*3072 aliases qkvb+attn
    unsigned short* qkv_wt  = (unsigned short*)(wsb + 251658240);    // [2304,768]  3,538,944
    unsigned short* proj_wt = (unsigned short*)(wsb + 255197184);    // [768,768]   1,179,648
    unsigned short* fc1_wt  = (unsigned short*)(wsb + 256376832);    // [3072,768]  4,718,592
    unsigned short* fc2_wt  = (unsigned short*)(wsb + 261095424);    // [768,3072]  4,718,592
    unsigned short* xln     = (unsigned short*)d_out;                // bf16 T*768 in d_out (free until step 5)

    // 0) weight prep
    wconv<<<dim3(2304 / 32, 768 / 32), 256, 0, stream>>>(qkv_w, qkv_wt, DIMD, 2304);
    wconv<<<dim3(768 / 32, 768 / 32), 256, 0, stream>>>(proj_w, proj_wt, DIMD, DIMD);
    wconv<<<dim3(3072 / 32, 768 / 32), 256, 0, stream>>>(fc1_w, fc1_wt, DIMD, HIDDEN);
    wconv<<<dim3(768 / 32, 3072 / 32), 256, 0, stream>>>(fc2_w, fc2_wt, HIDDEN, DIMD);
    wprep<<<dim3(MFEAT / 32, HDIM / 32, HEADS), 256, 0, stream>>>(w_orf, worf_ts);
    // 1) xln = LN1(x) (bf16, in d_out)
    ln_bf16<<<NTOK, 256, 0, stream>>>(x, ln1_g, ln1_b, xln);
    // 2) qkv = xln @ qkv_w + qkv_b (bf16)
    gemm_mfma<0, false, true><<<dim3(2304 / 128, NTOK / 128), 256, 0, stream>>>(
        xln, qkv_wt, qkv_b, nullptr, qkvb, DIMD, 2304);
    // 3) phase A: ktvT (incl. ksum row)
    ktv_mfma<<<dim3(HEADS, BATCH), 256, 0, stream>>>(qkvb, worf_ts, ktvT);
    // 4) phase B: attn out (bf16)
    attn_out_mfma<<<dim3(SEQ / 128, HEADS, BATCH), 256, 0, stream>>>(
        qkvb, worf_ts, ktvT, attn);
    // 5) h = x + attn @ proj_w + proj_b -> d_out (f32)
    gemm_mfma<0, true, false><<<dim3(DIMD / 128, NTOK / 128), 256, 0, stream>>>(
        attn, proj_wt, proj_b, x, out, DIMD, DIMD);
    // 6) y2 = LN2(h) (bf16)
    ln_bf16<<<NTOK, 256, 0, stream>>>(out, ln2_g, ln2_b, y2);
    // 7) hid = gelu(y2 @ fc1_w + fc1_b) (bf16)
    gemm_mfma<1, false, true><<<dim3(HIDDEN / 128, NTOK / 128), 256, 0, stream>>>(
        y2, fc1_wt, fc1_b, nullptr, hid, DIMD, HIDDEN);
    // 8) out = h + hid @ fc2_w + fc2_b (in-place residual on d_out)
    gemm_mfma<0, true, false><<<dim3(DIMD / 128, NTOK / 128), 256, 0, stream>>>(
        hid, fc2_wt, fc2_b, out, out, HIDDEN, DIMD);
}

// Round 7
// 1018.026 us; speedup vs baseline: 1.0310x; 1.0145x over previous
//
#include <hip/hip_runtime.h>
#include <hip/hip_bf16.h>

// Problem constants
#define NTOK   32768          // 32 * 1024 tokens
#define BATCH  32
#define SEQ    1024
#define DIMD   768
#define HEADS  12
#define HDIM   64
#define MFEAT  384
#define HIDDEN 3072
#define SCALE  0.35355339059327379f   // 64^-0.25
#define HALF_SCALE2 0.0625f           // 0.5 * SCALE^2
#define EPSP   3.84e-6f               // 1e-8 / RSM^2 (RSM factors cancel in out)

typedef __attribute__((ext_vector_type(8))) short bf16x8;
typedef __attribute__((ext_vector_type(4))) float f32x4;

static __device__ __forceinline__ float bf2f(unsigned short u) {
    return __uint_as_float(((unsigned)u) << 16);
}
static __device__ __forceinline__ unsigned short f2bf(float f) {
    unsigned u = __float_as_uint(f);
    return (unsigned short)((u + 0x7FFFu + ((u >> 16) & 1u)) >> 16);  // RNE
}
// gelu tanh-approx, exp form: 0.5v(1+tanh(u)) == v / (1 + e^{-2u})
static __device__ __forceinline__ float gelu_fast(float v) {
    const float c = 0.7978845608028654f;
    const float u = c * v * (1.0f + 0.044715f * v * v);
    return v / (1.0f + __expf(-2.0f * u));
}
static __device__ __forceinline__ void gload16(const void* g, void* l) {
    __builtin_amdgcn_global_load_lds(
        (const __attribute__((address_space(1))) void*)g,
        (__attribute__((address_space(3))) void*)l, 16, 0, 0);
}

// ---------------- fused LayerNorm -> bf16 (one block per 768-elem row) -----
__global__ __launch_bounds__(256) void ln_bf16(
    const float* __restrict__ x, const float* __restrict__ g,
    const float* __restrict__ bta, unsigned short* __restrict__ o) {
    const size_t row = blockIdx.x;
    const float* xr = x + row * DIMD;
    unsigned short* orow = o + row * DIMD;
    const int t = threadIdx.x;
    const float v0 = xr[t], v1 = xr[t + 256], v2 = xr[t + 512];
    float s  = v0 + v1 + v2;
    float sq = v0 * v0 + v1 * v1 + v2 * v2;
    const int lane = t & 63, w = t >> 6;
    #pragma unroll
    for (int off = 32; off > 0; off >>= 1) {
        s  += __shfl_down(s, off, 64);
        sq += __shfl_down(sq, off, 64);
    }
    __shared__ float red[2][4];
    if (lane == 0) { red[0][w] = s; red[1][w] = sq; }
    __syncthreads();
    s  = red[0][0] + red[0][1] + red[0][2] + red[0][3];
    sq = red[1][0] + red[1][1] + red[1][2] + red[1][3];
    const float mu  = s * (1.0f / DIMD);
    const float var = sq * (1.0f / DIMD) - mu * mu;
    const float r = rsqrtf(var + 1e-5f);
    orow[t]       = f2bf((v0 - mu) * r * g[t]       + bta[t]);
    orow[t + 256] = f2bf((v1 - mu) * r * g[t + 256] + bta[t + 256]);
    orow[t + 512] = f2bf((v2 - mu) * r * g[t + 512] + bta[t + 512]);
}

// ---------------- weight convert + transpose: W[K,N] f32 -> Wt[N,K] bf16 ---
__global__ __launch_bounds__(256) void wconv(
    const float* __restrict__ W, unsigned short* __restrict__ Wt, int K, int N) {
    __shared__ float tile[32][33];
    const int n0 = blockIdx.x << 5, k0 = blockIdx.y << 5;
    const int tn = threadIdx.x & 31, tg = threadIdx.x >> 5;   // tg 0..7
    #pragma unroll
    for (int i = 0; i < 4; ++i) {
        const int k = (tg << 2) + i;
        tile[k][tn] = W[(size_t)(k0 + k) * N + n0 + tn];
    }
    __syncthreads();
    #pragma unroll
    for (int i = 0; i < 4; ++i) {
        const int n = (tg << 2) + i;
        Wt[(size_t)(n0 + n) * K + k0 + tn] = f2bf(tile[tn][n]);
    }
}

// ---------------- worf prep: worf_ts[h][m][c] = bf16(SCALE * worf[h][c][m])
__global__ __launch_bounds__(256) void wprep(
    const float* __restrict__ worf, unsigned short* __restrict__ worf_ts) {
    __shared__ float tile[32][33];
    const int m0 = blockIdx.x << 5, c0 = blockIdx.y << 5, h = blockIdx.z;
    const int tn = threadIdx.x & 31, tg = threadIdx.x >> 5;
    #pragma unroll
    for (int i = 0; i < 4; ++i) {
        const int c = (tg << 2) + i;
        tile[c][tn] = worf[(size_t)(h * HDIM + c0 + c) * MFEAT + m0 + tn];
    }
    __syncthreads();
    #pragma unroll
    for (int i = 0; i < 4; ++i) {
        const int m = (tg << 2) + i;
        worf_ts[(size_t)(h * MFEAT + m0 + m) * HDIM + c0 + tn] =
            f2bf(SCALE * tile[tn][m]);
    }
}

// ---------------- bf16 MFMA GEMM: C = A[M,K] @ Wt[N,K]^T + bias ------------
// 256x128 block tile, BK=32, 4 waves, wave owns 128x64 (8x4 frags of
// 16x16x32). Double-buffered LDS (48 KB), global_load_lds width-16 staging.
// 2.1 MFLOP per barrier-pair (2x the 128^2 structure) -> halves stall frac.
template <int ACT, bool RES, bool OBF16>
__global__ __launch_bounds__(256, 2) void gemm_mfma(
    const unsigned short* __restrict__ A, const unsigned short* __restrict__ Wt,
    const float* __restrict__ bias, const float* __restrict__ resid,
    void* __restrict__ Craw, int K, int N) {
    __shared__ unsigned short As[2][256 * 32];   // 16 KB per buffer
    __shared__ unsigned short Bs[2][128 * 32];   //  8 KB per buffer
    const int t = threadIdx.x;
    const int w = t >> 6, l = t & 63;
    const int row0 = blockIdx.y << 8, col0 = blockIdx.x << 7;
    const int wrow = (w >> 1) << 7, wcol = (w & 1) << 6;   // wave tile origin

    // staging: wave w covers A rows [w*64, w*64+64), B rows [w*32, w*32+32)
    // lane l -> row (l>>2) within a 16-row chunk, 16B piece (l&3) of 64B row
    const unsigned short* ag[4];
    const unsigned short* bg[2];
    #pragma unroll
    for (int cch = 0; cch < 4; ++cch)
        ag[cch] = A + (size_t)(row0 + w * 64 + cch * 16 + (l >> 2)) * K + ((l & 3) << 3);
    #pragma unroll
    for (int cch = 0; cch < 2; ++cch)
        bg[cch] = Wt + (size_t)(col0 + w * 32 + cch * 16 + (l >> 2)) * K + ((l & 3) << 3);

    f32x4 acc[8][4] = {};
    const int NT = K >> 5;

    auto stage = [&](int bi, int s) {
        const size_t ko = (size_t)s << 5;   // 32 bf16 per K-step
        #pragma unroll
        for (int cch = 0; cch < 4; ++cch)
            gload16(ag[cch] + ko, &As[bi][(w * 64 + cch * 16) * 32]);
        #pragma unroll
        for (int cch = 0; cch < 2; ++cch)
            gload16(bg[cch] + ko, &Bs[bi][(w * 32 + cch * 16) * 32]);
    };

    stage(0, 0);
    const int lr = l & 15, lk = (l >> 4) << 3, lg = l >> 4;
    for (int s = 0; s < NT; ++s) {
        __syncthreads();                       // buf[s&1] staged; prior reads of buf[(s+1)&1] done
        if (s + 1 < NT) stage((s + 1) & 1, s + 1);
        const unsigned short* ab = &As[s & 1][0];
        const unsigned short* bb = &Bs[s & 1][0];
        bf16x8 af[8], bfr[4];
        #pragma unroll
        for (int fi = 0; fi < 8; ++fi)
            af[fi] = *(const bf16x8*)(ab + (wrow + fi * 16 + lr) * 32 + lk);
        #pragma unroll
        for (int fj = 0; fj < 4; ++fj)
            bfr[fj] = *(const bf16x8*)(bb + (wcol + fj * 16 + lr) * 32 + lk);
        #pragma unroll
        for (int fi = 0; fi < 8; ++fi)
            #pragma unroll
            for (int fj = 0; fj < 4; ++fj)
                acc[fi][fj] = __builtin_amdgcn_mfma_f32_16x16x32_bf16(
                    af[fi], bfr[fj], acc[fi][fj], 0, 0, 0);
    }

    float bv[4];
    #pragma unroll
    for (int fj = 0; fj < 4; ++fj) bv[fj] = bias[col0 + wcol + fj * 16 + lr];
    #pragma unroll
    for (int fi = 0; fi < 8; ++fi) {
        #pragma unroll
        for (int r = 0; r < 4; ++r) {
            const int row = row0 + wrow + fi * 16 + lg * 4 + r;
            const size_t base = (size_t)row * N + col0 + wcol + lr;
            #pragma unroll
            for (int fj = 0; fj < 4; ++fj) {
                float v = acc[fi][fj][r] + bv[fj];
                if constexpr (RES) v += resid[base + fj * 16];
                if constexpr (ACT == 1) v = gelu_fast(v);
                if constexpr (OBF16) ((unsigned short*)Craw)[base + fj * 16] = f2bf(v);
                else                 ((float*)Craw)[base + fj * 16] = v;
            }
        }
    }
}

// ---------------- Phase A (MFMA): per (b,h): ktvT[c][m] (+ksum row 64) -----
__global__ __launch_bounds__(256, 1) void ktv_mfma(
    const unsigned short* __restrict__ qkvb,
    const unsigned short* __restrict__ worf_ts,
    unsigned short* __restrict__ ktvT) {
    const int h = blockIdx.x, b = blockIdx.y, bh = b * HEADS + h;
    __shared__ __align__(16) unsigned short Klds[32][72];
    __shared__ __align__(16) unsigned short VT[80][40];
    __shared__ __align__(16) unsigned short P[4][96][40];
    const int t = threadIdx.x, w = t >> 6, l = t & 63;
    const int lr = l & 15, lg = l >> 4;
    const int m0 = w * 96;

    bf16x8 bfw[6][2];
    #pragma unroll
    for (int mt = 0; mt < 6; ++mt)
        #pragma unroll
        for (int ks = 0; ks < 2; ++ks)
            bfw[mt][ks] = *(const bf16x8*)(worf_ts +
                (size_t)(h * MFEAT + m0 + mt * 16 + lr) * HDIM + ks * 32 + lg * 8);

    f32x4 acc[5][6] = {};   // [c-tile][m-tile]

    for (int i = t; i < 16 * 40; i += 256) {
        const int r = 64 + i / 40, cc = i % 40;
        VT[r][cc] = (r == 64) ? (unsigned short)0x3F80 : (unsigned short)0;
    }
    const unsigned short* kglob = qkvb + (size_t)b * SEQ * 2304 + 768 + h * 64;
    const unsigned short* vglob = kglob + 768;

    for (int n0 = 0; n0 < SEQ; n0 += 32) {
        __syncthreads();
        {   // stage K tile [32][64]
            const int row = t >> 3, c8 = (t & 7) << 3;
            *(bf16x8*)&Klds[row][c8] =
                *(const bf16x8*)(kglob + (size_t)(n0 + row) * 2304 + c8);
        }
        {   // stage V^T tile [c][n]
            const int n = t & 31, c0 = (t >> 5) << 3;
            const unsigned short* src = vglob + (size_t)(n0 + n) * 2304 + c0;
            ushort4 v0 = *(const ushort4*)src;
            ushort4 v1 = *(const ushort4*)(src + 4);
            VT[c0 + 0][n] = v0.x; VT[c0 + 1][n] = v0.y;
            VT[c0 + 2][n] = v0.z; VT[c0 + 3][n] = v0.w;
            VT[c0 + 4][n] = v1.x; VT[c0 + 5][n] = v1.y;
            VT[c0 + 6][n] = v1.z; VT[c0 + 7][n] = v1.w;
        }
        __syncthreads();

        bf16x8 afk[2][2];
        float sqv[2][4];
        #pragma unroll
        for (int ns = 0; ns < 2; ++ns) {
            float s = 0.f;
            #pragma unroll
            for (int ks = 0; ks < 2; ++ks) {
                afk[ns][ks] = *(const bf16x8*)&Klds[ns * 16 + lr][ks * 32 + lg * 8];
                #pragma unroll
                for (int j = 0; j < 8; ++j) {
                    const float f = bf2f((unsigned short)afk[ns][ks][j]);
                    s += f * f;
                }
            }
            s += __shfl_xor(s, 16);
            s += __shfl_xor(s, 32);
            s *= HALF_SCALE2;
            #pragma unroll
            for (int r = 0; r < 4; ++r)
                sqv[ns][r] = __shfl(s, (lg << 2) + r);
        }

        #pragma unroll
        for (int mt = 0; mt < 6; ++mt) {
            #pragma unroll
            for (int ns = 0; ns < 2; ++ns) {
                f32x4 p = {};
                p = __builtin_amdgcn_mfma_f32_16x16x32_bf16(afk[ns][0], bfw[mt][0], p, 0, 0, 0);
                p = __builtin_amdgcn_mfma_f32_16x16x32_bf16(afk[ns][1], bfw[mt][1], p, 0, 0, 0);
                ushort4 pk;
                pk.x = f2bf(__expf(p[0] - sqv[ns][0]));
                pk.y = f2bf(__expf(p[1] - sqv[ns][1]));
                pk.z = f2bf(__expf(p[2] - sqv[ns][2]));
                pk.w = f2bf(__expf(p[3] - sqv[ns][3]));
                *(ushort4*)&P[w][mt * 16 + lr][ns * 16 + lg * 4] = pk;
            }
        }
        asm volatile("s_waitcnt lgkmcnt(0)" ::: "memory");
        __builtin_amdgcn_sched_barrier(0);

        bf16x8 afv[5];
        #pragma unroll
        for (int ct = 0; ct < 5; ++ct)
            afv[ct] = *(const bf16x8*)&VT[ct * 16 + lr][lg * 8];
        #pragma unroll
        for (int mt = 0; mt < 6; ++mt) {
            const bf16x8 bp = *(const bf16x8*)&P[w][mt * 16 + lr][lg * 8];
            #pragma unroll
            for (int ct = 0; ct < 5; ++ct)
                acc[ct][mt] = __builtin_amdgcn_mfma_f32_16x16x32_bf16(afv[ct], bp, acc[ct][mt], 0, 0, 0);
        }
    }

    unsigned short* dst = ktvT + (size_t)bh * 80 * MFEAT;
    #pragma unroll
    for (int ct = 0; ct < 5; ++ct)
        #pragma unroll
        for (int mt = 0; mt < 6; ++mt)
            #pragma unroll
            for (int r = 0; r < 4; ++r) {
                const int cc = ct * 16 + lg * 4 + r;
                const int m = m0 + mt * 16 + lr;
                dst[(size_t)cc * MFEAT + m] = f2bf(acc[ct][mt][r]);
            }
}

// ---------------- Phase B (MFMA): out^T[c,n] = sum_m ktvT[c,m] * phi_q[n,m]
__global__ __launch_bounds__(256) void attn_out_mfma(
    const unsigned short* __restrict__ qkvb,
    const unsigned short* __restrict__ worf_ts,
    const unsigned short* __restrict__ ktvT,
    unsigned short* __restrict__ attn) {
    const int n0 = blockIdx.x << 7;
    const int h = blockIdx.y, b = blockIdx.z, bh = b * HEADS + h;
    __shared__ __align__(16) unsigned short KT[80][104];
    __shared__ __align__(16) unsigned short P[4][32][104];
    const int t = threadIdx.x, w = t >> 6, l = t & 63;
    const int lr = l & 15, lg = l >> 4;
    const int nw = n0 + w * 32;

    bf16x8 bq[2][2];
    float sqn[2];
    #pragma unroll
    for (int nt = 0; nt < 2; ++nt) {
        float s = 0.f;
        #pragma unroll
        for (int ks = 0; ks < 2; ++ks) {
            bq[nt][ks] = *(const bf16x8*)(qkvb +
                (size_t)(b * SEQ + nw + nt * 16 + lr) * 2304 + h * 64 + ks * 32 + lg * 8);
            #pragma unroll
            for (int j = 0; j < 8; ++j) {
                const float f = bf2f((unsigned short)bq[nt][ks][j]);
                s += f * f;
            }
        }
        s += __shfl_xor(s, 16);
        s += __shfl_xor(s, 32);
        sqn[nt] = s * HALF_SCALE2;
    }

    f32x4 acc[5][2] = {};
    const unsigned short* ktg = ktvT + (size_t)bh * 80 * MFEAT;

    for (int ch = 0; ch < 4; ++ch) {
        const int m0 = ch * 96;
        __syncthreads();
        for (int i = t; i < 1920; i += 256) {
            const int row = i / 24, q = i % 24;
            *(ushort4*)&KT[row][q * 4] =
                *(const ushort4*)(ktg + (size_t)row * MFEAT + m0 + q * 4);
        }
        __syncthreads();

        #pragma unroll
        for (int mt = 0; mt < 6; ++mt) {
            bf16x8 afw[2];
            #pragma unroll
            for (int ks = 0; ks < 2; ++ks)
                afw[ks] = *(const bf16x8*)(worf_ts +
                    (size_t)(h * MFEAT + m0 + mt * 16 + lr) * HDIM + ks * 32 + lg * 8);
            #pragma unroll
            for (int nt = 0; nt < 2; ++nt) {
                f32x4 p = {};
                p = __builtin_amdgcn_mfma_f32_16x16x32_bf16(afw[0], bq[nt][0], p, 0, 0, 0);
                p = __builtin_amdgcn_mfma_f32_16x16x32_bf16(afw[1], bq[nt][1], p, 0, 0, 0);
                ushort4 pk;
                pk.x = f2bf(__expf(p[0] - sqn[nt]));
                pk.y = f2bf(__expf(p[1] - sqn[nt]));
                pk.z = f2bf(__expf(p[2] - sqn[nt]));
                pk.w = f2bf(__expf(p[3] - sqn[nt]));
                *(ushort4*)&P[w][nt * 16 + lr][mt * 16 + lg * 4] = pk;
            }
        }
        asm volatile("s_waitcnt lgkmcnt(0)" ::: "memory");
        __builtin_amdgcn_sched_barrier(0);

        #pragma unroll
        for (int ks = 0; ks < 3; ++ks) {
            bf16x8 bp[2];
            #pragma unroll
            for (int nt = 0; nt < 2; ++nt)
                bp[nt] = *(const bf16x8*)&P[w][nt * 16 + lr][ks * 32 + lg * 8];
            #pragma unroll
            for (int ct = 0; ct < 5; ++ct) {
                const bf16x8 av = *(const bf16x8*)&KT[ct * 16 + lr][ks * 32 + lg * 8];
                #pragma unroll
                for (int nt = 0; nt < 2; ++nt)
                    acc[ct][nt] = __builtin_amdgcn_mfma_f32_16x16x32_bf16(av, bp[nt], acc[ct][nt], 0, 0, 0);
            }
        }
    }

    #pragma unroll
    for (int nt = 0; nt < 2; ++nt) {
        const float d = __shfl(acc[4][nt][0], lr);
        const float inv = 1.0f / (d + EPSP);
        const int token = b * SEQ + nw + nt * 16 + lr;
        #pragma unroll
        for (int ct = 0; ct < 4; ++ct)
            #pragma unroll
            for (int r = 0; r < 4; ++r) {
                const int cc = ct * 16 + lg * 4 + r;
                attn[(size_t)token * DIMD + h * 64 + cc] = f2bf(acc[ct][nt][r] * inv);
            }
    }
}

// ---------------------------------------------------------------------------
extern "C" void kernel_launch(void* const* d_in, const int* in_sizes, int n_in,
                              void* d_out, int out_size, void* d_ws, size_t ws_size,
                              hipStream_t stream) {
    const float* x      = (const float*)d_in[0];
    const float* ln1_g  = (const float*)d_in[1];
    const float* ln1_b  = (const float*)d_in[2];
    const float* qkv_w  = (const float*)d_in[3];
    const float* qkv_b  = (const float*)d_in[4];
    const float* w_orf  = (const float*)d_in[5];
    const float* proj_w = (const float*)d_in[6];
    const float* proj_b = (const float*)d_in[7];
    const float* ln2_g  = (const float*)d_in[8];
    const float* ln2_b  = (const float*)d_in[9];
    const float* fc1_w  = (const float*)d_in[10];
    const float* fc1_b  = (const float*)d_in[11];
    const float* fc2_w  = (const float*)d_in[12];
    const float* fc2_b  = (const float*)d_in[13];
    float* out = (float*)d_out;

    // Workspace layout (bytes), total 265,814,016 B (= round-3 proven size).
    char* wsb = (char*)d_ws;
    unsigned short* qkvb    = (unsigned short*)wsb;                  // bf16 T*2304 [0, 150994944)
    unsigned short* attn    = (unsigned short*)(wsb + 150994944);    // bf16 T*768  [.., 201326592)
    unsigned short* ktvT    = (unsigned short*)(wsb + 201326592);    // bf16 384*80*384 = 23,592,960
    unsigned short* worf_ts = (unsigned short*)(wsb + 224919552);    // bf16 12*384*64 = 589,824
    unsigned short* y2      = (unsigned short*)(wsb + 201326592);    // LN2 out (ktvT/worf_ts dead)
    unsigned short* hid     = qkvb;                                  // bf16 T*3072 aliases qkvb+attn
    unsigned short* qkv_wt  = (unsigned short*)(wsb + 251658240);    // [2304,768]  3,538,944
    unsigned short* proj_wt = (unsigned short*)(wsb + 255197184);    // [768,768]   1,179,648
    unsigned short* fc1_wt  = (unsigned short*)(wsb + 256376832);    // [3072,768]  4,718,592
    unsigned short* fc2_wt  = (unsigned short*)(wsb + 261095424);    // [768,3072]  4,718,592
    unsigned short* xln     = (unsigned short*)d_out;                // bf16 T*768 in d_out (free until step 5)

    // 0) weight prep
    wconv<<<dim3(2304 / 32, 768 / 32), 256, 0, stream>>>(qkv_w, qkv_wt, DIMD, 2304);
    wconv<<<dim3(768 / 32, 768 / 32), 256, 0, stream>>>(proj_w, proj_wt, DIMD, DIMD);
    wconv<<<dim3(3072 / 32, 768 / 32), 256, 0, stream>>>(fc1_w, fc1_wt, DIMD, HIDDEN);
    wconv<<<dim3(768 / 32, 3072 / 32), 256, 0, stream>>>(fc2_w, fc2_wt, HIDDEN, DIMD);
    wprep<<<dim3(MFEAT / 32, HDIM / 32, HEADS), 256, 0, stream>>>(w_orf, worf_ts);
    // 1) xln = LN1(x) (bf16, in d_out)
    ln_bf16<<<NTOK, 256, 0, stream>>>(x, ln1_g, ln1_b, xln);
    // 2) qkv = xln @ qkv_w + qkv_b (bf16)
    gemm_mfma<0, false, true><<<dim3(2304 / 128, NTOK / 256), 256, 0, stream>>>(
        xln, qkv_wt, qkv_b, nullptr, qkvb, DIMD, 2304);
    // 3) phase A: ktvT (incl. ksum row)
    ktv_mfma<<<dim3(HEADS, BATCH), 256, 0, stream>>>(qkvb, worf_ts, ktvT);
    // 4) phase B: attn out (bf16)
    attn_out_mfma<<<dim3(SEQ / 128, HEADS, BATCH), 256, 0, stream>>>(
        qkvb, worf_ts, ktvT, attn);
    // 5) h = x + attn @ proj_w + proj_b -> d_out (f32)
    gemm_mfma<0, true, false><<<dim3(DIMD / 128, NTOK / 256), 256, 0, stream>>>(
        attn, proj_wt, proj_b, x, out, DIMD, DIMD);
    // 6) y2 = LN2(h) (bf16)
    ln_bf16<<<NTOK, 256, 0, stream>>>(out, ln2_g, ln2_b, y2);
    // 7) hid = gelu(y2 @ fc1_w + fc1_b) (bf16)
    gemm_mfma<1, false, true><<<dim3(HIDDEN / 128, NTOK / 256), 256, 0, stream>>>(
        y2, fc1_wt, fc1_b, nullptr, hid, DIMD, HIDDEN);
    // 8) out = h + hid @ fc2_w + fc2_b (in-place residual on d_out)
    gemm_mfma<0, true, false><<<dim3(DIMD / 128, NTOK / 256), 256, 0, stream>>>(
        hid, fc2_wt, fc2_b, out, out, HIDDEN, DIMD);
}

// Round 8
// 986.560 us; speedup vs baseline: 1.0639x; 1.0319x over previous
//
#include <hip/hip_runtime.h>
#include <hip/hip_bf16.h>

// Problem constants
#define NTOK   32768          // 32 * 1024 tokens
#define BATCH  32
#define SEQ    1024
#define DIMD   768
#define HEADS  12
#define HDIM   64
#define MFEAT  384
#define HIDDEN 3072
#define SCALE  0.35355339059327379f   // 64^-0.25
#define HALF_SCALE2 0.0625f           // 0.5 * SCALE^2
#define EPSP   3.84e-6f               // 1e-8 / RSM^2 (RSM factors cancel in out)

typedef __attribute__((ext_vector_type(8))) short bf16x8;
typedef __attribute__((ext_vector_type(4))) float f32x4;

static __device__ __forceinline__ float bf2f(unsigned short u) {
    return __uint_as_float(((unsigned)u) << 16);
}
static __device__ __forceinline__ unsigned short f2bf(float f) {
    unsigned u = __float_as_uint(f);
    return (unsigned short)((u + 0x7FFFu + ((u >> 16) & 1u)) >> 16);  // RNE
}
// gelu tanh-approx, exp form: 0.5v(1+tanh(u)) == v / (1 + e^{-2u})
static __device__ __forceinline__ float gelu_fast(float v) {
    const float c = 0.7978845608028654f;
    const float u = c * v * (1.0f + 0.044715f * v * v);
    return v / (1.0f + __expf(-2.0f * u));
}
static __device__ __forceinline__ void gload16(const void* g, void* l) {
    __builtin_amdgcn_global_load_lds(
        (const __attribute__((address_space(1))) void*)g,
        (__attribute__((address_space(3))) void*)l, 16, 0, 0);
}

// ---------------- fused LayerNorm -> bf16 (one block per 768-elem row) -----
__global__ __launch_bounds__(256) void ln_bf16(
    const float* __restrict__ x, const float* __restrict__ g,
    const float* __restrict__ bta, unsigned short* __restrict__ o) {
    const size_t row = blockIdx.x;
    const float* xr = x + row * DIMD;
    unsigned short* orow = o + row * DIMD;
    const int t = threadIdx.x;
    const float v0 = xr[t], v1 = xr[t + 256], v2 = xr[t + 512];
    float s  = v0 + v1 + v2;
    float sq = v0 * v0 + v1 * v1 + v2 * v2;
    const int lane = t & 63, w = t >> 6;
    #pragma unroll
    for (int off = 32; off > 0; off >>= 1) {
        s  += __shfl_down(s, off, 64);
        sq += __shfl_down(sq, off, 64);
    }
    __shared__ float red[2][4];
    if (lane == 0) { red[0][w] = s; red[1][w] = sq; }
    __syncthreads();
    s  = red[0][0] + red[0][1] + red[0][2] + red[0][3];
    sq = red[1][0] + red[1][1] + red[1][2] + red[1][3];
    const float mu  = s * (1.0f / DIMD);
    const float var = sq * (1.0f / DIMD) - mu * mu;
    const float r = rsqrtf(var + 1e-5f);
    orow[t]       = f2bf((v0 - mu) * r * g[t]       + bta[t]);
    orow[t + 256] = f2bf((v1 - mu) * r * g[t + 256] + bta[t + 256]);
    orow[t + 512] = f2bf((v2 - mu) * r * g[t + 512] + bta[t + 512]);
}

// ---------------- weight convert + transpose: W[K,N] f32 -> Wt[N,K] bf16 ---
__global__ __launch_bounds__(256) void wconv(
    const float* __restrict__ W, unsigned short* __restrict__ Wt, int K, int N) {
    __shared__ float tile[32][33];
    const int n0 = blockIdx.x << 5, k0 = blockIdx.y << 5;
    const int tn = threadIdx.x & 31, tg = threadIdx.x >> 5;   // tg 0..7
    #pragma unroll
    for (int i = 0; i < 4; ++i) {
        const int k = (tg << 2) + i;
        tile[k][tn] = W[(size_t)(k0 + k) * N + n0 + tn];
    }
    __syncthreads();
    #pragma unroll
    for (int i = 0; i < 4; ++i) {
        const int n = (tg << 2) + i;
        Wt[(size_t)(n0 + n) * K + k0 + tn] = f2bf(tile[tn][n]);
    }
}

// ---------------- worf prep: worf_ts[h][m][c] = bf16(SCALE * worf[h][c][m])
__global__ __launch_bounds__(256) void wprep(
    const float* __restrict__ worf, unsigned short* __restrict__ worf_ts) {
    __shared__ float tile[32][33];
    const int m0 = blockIdx.x << 5, c0 = blockIdx.y << 5, h = blockIdx.z;
    const int tn = threadIdx.x & 31, tg = threadIdx.x >> 5;
    #pragma unroll
    for (int i = 0; i < 4; ++i) {
        const int c = (tg << 2) + i;
        tile[c][tn] = worf[(size_t)(h * HDIM + c0 + c) * MFEAT + m0 + tn];
    }
    __syncthreads();
    #pragma unroll
    for (int i = 0; i < 4; ++i) {
        const int m = (tg << 2) + i;
        worf_ts[(size_t)(h * MFEAT + m0 + m) * HDIM + c0 + tn] =
            f2bf(SCALE * tile[tn][m]);
    }
}

// ---------------- bf16 MFMA GEMM: C = A[M,K] @ Wt[N,K]^T + bias ------------
// 256x128 block tile, BK=32, 4 waves, wave owns 128x64 (8x4 frags).
// TRIPLE-buffered LDS (72 KB), depth-2 prefetch, counted vmcnt(6), ONE raw
// barrier per iteration (stage issued AFTER barrier so the barrier doubles
// as read-complete fence for the buffer being overwritten).
// XCD-chunked block swizzle: each XCD gets a contiguous band of row-stripes
// (all col tiles) -> 8 disjoint A windows, L3-resident, ~1x A HBM traffic.
template <int ACT, bool RES, bool OBF16>
__global__ __launch_bounds__(256, 2) void gemm_mfma(
    const unsigned short* __restrict__ A, const unsigned short* __restrict__ Wt,
    const float* __restrict__ bias, const float* __restrict__ resid,
    void* __restrict__ Craw, int K, int N) {
    __shared__ unsigned short As[3][256 * 32];   // 16 KB per buffer
    __shared__ unsigned short Bs[3][128 * 32];   //  8 KB per buffer
    const int t = threadIdx.x;
    const int w = t >> 6, l = t & 63;
    // XCD-chunked swizzle (all our grids have nwg % 8 == 0)
    const int ncol = gridDim.x;
    const int lin = blockIdx.y * ncol + blockIdx.x;
    const int cpx = (ncol * gridDim.y) >> 3;
    const int wg = (lin & 7) * cpx + (lin >> 3);
    const int row0 = (wg / ncol) << 8, col0 = (wg % ncol) << 7;
    const int wrow = (w >> 1) << 7, wcol = (w & 1) << 6;   // wave tile origin

    // staging: wave w covers A rows [w*64, w*64+64), B rows [w*32, w*32+32)
    const unsigned short* ag[4];
    const unsigned short* bg[2];
    #pragma unroll
    for (int cch = 0; cch < 4; ++cch)
        ag[cch] = A + (size_t)(row0 + w * 64 + cch * 16 + (l >> 2)) * K + ((l & 3) << 3);
    #pragma unroll
    for (int cch = 0; cch < 2; ++cch)
        bg[cch] = Wt + (size_t)(col0 + w * 32 + cch * 16 + (l >> 2)) * K + ((l & 3) << 3);

    f32x4 acc[8][4] = {};
    const int NT = K >> 5;

    auto stage = [&](int bi, int s) {
        const size_t ko = (size_t)s << 5;   // 32 bf16 per K-step
        #pragma unroll
        for (int cch = 0; cch < 4; ++cch)
            gload16(ag[cch] + ko, &As[bi][(w * 64 + cch * 16) * 32]);
        #pragma unroll
        for (int cch = 0; cch < 2; ++cch)
            gload16(bg[cch] + ko, &Bs[bi][(w * 32 + cch * 16) * 32]);
    };

    stage(0, 0);
    stage(1, 1);
    const int lr = l & 15, lk = (l >> 4) << 3, lg = l >> 4;
    int cur = 0;   // buffer holding tile s
    for (int s = 0; s < NT; ++s) {
        // wait for tile s's 6 loads; tile s+1's 6 stay in flight
        if (s + 1 < NT) asm volatile("s_waitcnt vmcnt(6)" ::: "memory");
        else            asm volatile("s_waitcnt vmcnt(0)" ::: "memory");
        __builtin_amdgcn_s_barrier();            // tile s fully in LDS; prior reads of buf (s+2)%3 done
        __builtin_amdgcn_sched_barrier(0);       // nothing hoists above the barrier
        if (s + 2 < NT) {
            int sb = cur + 2; if (sb >= 3) sb -= 3;
            stage(sb, s + 2);                    // ~2 iterations of flight time
        }
        const unsigned short* ab = &As[cur][0];
        const unsigned short* bb = &Bs[cur][0];
        bf16x8 af[8], bfr[4];
        #pragma unroll
        for (int fi = 0; fi < 8; ++fi)
            af[fi] = *(const bf16x8*)(ab + (wrow + fi * 16 + lr) * 32 + lk);
        #pragma unroll
        for (int fj = 0; fj < 4; ++fj)
            bfr[fj] = *(const bf16x8*)(bb + (wcol + fj * 16 + lr) * 32 + lk);
        #pragma unroll
        for (int fi = 0; fi < 8; ++fi)
            #pragma unroll
            for (int fj = 0; fj < 4; ++fj)
                acc[fi][fj] = __builtin_amdgcn_mfma_f32_16x16x32_bf16(
                    af[fi], bfr[fj], acc[fi][fj], 0, 0, 0);
        cur = (cur + 1 == 3) ? 0 : cur + 1;
    }

    float bv[4];
    #pragma unroll
    for (int fj = 0; fj < 4; ++fj) bv[fj] = bias[col0 + wcol + fj * 16 + lr];
    #pragma unroll
    for (int fi = 0; fi < 8; ++fi) {
        #pragma unroll
        for (int r = 0; r < 4; ++r) {
            const int row = row0 + wrow + fi * 16 + lg * 4 + r;
            const size_t base = (size_t)row * N + col0 + wcol + lr;
            #pragma unroll
            for (int fj = 0; fj < 4; ++fj) {
                float v = acc[fi][fj][r] + bv[fj];
                if constexpr (RES) v += resid[base + fj * 16];
                if constexpr (ACT == 1) v = gelu_fast(v);
                if constexpr (OBF16) ((unsigned short*)Craw)[base + fj * 16] = f2bf(v);
                else                 ((float*)Craw)[base + fj * 16] = v;
            }
        }
    }
}

// ---------------- Phase A (MFMA): per (b,h): ktvT[c][m] (+ksum row 64) -----
__global__ __launch_bounds__(256, 1) void ktv_mfma(
    const unsigned short* __restrict__ qkvb,
    const unsigned short* __restrict__ worf_ts,
    unsigned short* __restrict__ ktvT) {
    const int h = blockIdx.x, b = blockIdx.y, bh = b * HEADS + h;
    __shared__ __align__(16) unsigned short Klds[32][72];
    __shared__ __align__(16) unsigned short VT[80][40];
    __shared__ __align__(16) unsigned short P[4][96][40];
    const int t = threadIdx.x, w = t >> 6, l = t & 63;
    const int lr = l & 15, lg = l >> 4;
    const int m0 = w * 96;

    bf16x8 bfw[6][2];
    #pragma unroll
    for (int mt = 0; mt < 6; ++mt)
        #pragma unroll
        for (int ks = 0; ks < 2; ++ks)
            bfw[mt][ks] = *(const bf16x8*)(worf_ts +
                (size_t)(h * MFEAT + m0 + mt * 16 + lr) * HDIM + ks * 32 + lg * 8);

    f32x4 acc[5][6] = {};   // [c-tile][m-tile]

    for (int i = t; i < 16 * 40; i += 256) {
        const int r = 64 + i / 40, cc = i % 40;
        VT[r][cc] = (r == 64) ? (unsigned short)0x3F80 : (unsigned short)0;
    }
    const unsigned short* kglob = qkvb + (size_t)b * SEQ * 2304 + 768 + h * 64;
    const unsigned short* vglob = kglob + 768;

    for (int n0 = 0; n0 < SEQ; n0 += 32) {
        __syncthreads();
        {   // stage K tile [32][64]
            const int row = t >> 3, c8 = (t & 7) << 3;
            *(bf16x8*)&Klds[row][c8] =
                *(const bf16x8*)(kglob + (size_t)(n0 + row) * 2304 + c8);
        }
        {   // stage V^T tile [c][n]
            const int n = t & 31, c0 = (t >> 5) << 3;
            const unsigned short* src = vglob + (size_t)(n0 + n) * 2304 + c0;
            ushort4 v0 = *(const ushort4*)src;
            ushort4 v1 = *(const ushort4*)(src + 4);
            VT[c0 + 0][n] = v0.x; VT[c0 + 1][n] = v0.y;
            VT[c0 + 2][n] = v0.z; VT[c0 + 3][n] = v0.w;
            VT[c0 + 4][n] = v1.x; VT[c0 + 5][n] = v1.y;
            VT[c0 + 6][n] = v1.z; VT[c0 + 7][n] = v1.w;
        }
        __syncthreads();

        bf16x8 afk[2][2];
        float sqv[2][4];
        #pragma unroll
        for (int ns = 0; ns < 2; ++ns) {
            float s = 0.f;
            #pragma unroll
            for (int ks = 0; ks < 2; ++ks) {
                afk[ns][ks] = *(const bf16x8*)&Klds[ns * 16 + lr][ks * 32 + lg * 8];
                #pragma unroll
                for (int j = 0; j < 8; ++j) {
                    const float f = bf2f((unsigned short)afk[ns][ks][j]);
                    s += f * f;
                }
            }
            s += __shfl_xor(s, 16);
            s += __shfl_xor(s, 32);
            s *= HALF_SCALE2;
            #pragma unroll
            for (int r = 0; r < 4; ++r)
                sqv[ns][r] = __shfl(s, (lg << 2) + r);
        }

        #pragma unroll
        for (int mt = 0; mt < 6; ++mt) {
            #pragma unroll
            for (int ns = 0; ns < 2; ++ns) {
                f32x4 p = {};
                p = __builtin_amdgcn_mfma_f32_16x16x32_bf16(afk[ns][0], bfw[mt][0], p, 0, 0, 0);
                p = __builtin_amdgcn_mfma_f32_16x16x32_bf16(afk[ns][1], bfw[mt][1], p, 0, 0, 0);
                ushort4 pk;
                pk.x = f2bf(__expf(p[0] - sqv[ns][0]));
                pk.y = f2bf(__expf(p[1] - sqv[ns][1]));
                pk.z = f2bf(__expf(p[2] - sqv[ns][2]));
                pk.w = f2bf(__expf(p[3] - sqv[ns][3]));
                *(ushort4*)&P[w][mt * 16 + lr][ns * 16 + lg * 4] = pk;
            }
        }
        asm volatile("s_waitcnt lgkmcnt(0)" ::: "memory");
        __builtin_amdgcn_sched_barrier(0);

        bf16x8 afv[5];
        #pragma unroll
        for (int ct = 0; ct < 5; ++ct)
            afv[ct] = *(const bf16x8*)&VT[ct * 16 + lr][lg * 8];
        #pragma unroll
        for (int mt = 0; mt < 6; ++mt) {
            const bf16x8 bp = *(const bf16x8*)&P[w][mt * 16 + lr][lg * 8];
            #pragma unroll
            for (int ct = 0; ct < 5; ++ct)
                acc[ct][mt] = __builtin_amdgcn_mfma_f32_16x16x32_bf16(afv[ct], bp, acc[ct][mt], 0, 0, 0);
        }
    }

    unsigned short* dst = ktvT + (size_t)bh * 80 * MFEAT;
    #pragma unroll
    for (int ct = 0; ct < 5; ++ct)
        #pragma unroll
        for (int mt = 0; mt < 6; ++mt)
            #pragma unroll
            for (int r = 0; r < 4; ++r) {
                const int cc = ct * 16 + lg * 4 + r;
                const int m = m0 + mt * 16 + lr;
                dst[(size_t)cc * MFEAT + m] = f2bf(acc[ct][mt][r]);
            }
}

// ---------------- Phase B (MFMA): out^T[c,n] = sum_m ktvT[c,m] * phi_q[n,m]
__global__ __launch_bounds__(256) void attn_out_mfma(
    const unsigned short* __restrict__ qkvb,
    const unsigned short* __restrict__ worf_ts,
    const unsigned short* __restrict__ ktvT,
    unsigned short* __restrict__ attn) {
    const int n0 = blockIdx.x << 7;
    const int h = blockIdx.y, b = blockIdx.z, bh = b * HEADS + h;
    __shared__ __align__(16) unsigned short KT[80][104];
    __shared__ __align__(16) unsigned short P[4][32][104];
    const int t = threadIdx.x, w = t >> 6, l = t & 63;
    const int lr = l & 15, lg = l >> 4;
    const int nw = n0 + w * 32;

    bf16x8 bq[2][2];
    float sqn[2];
    #pragma unroll
    for (int nt = 0; nt < 2; ++nt) {
        float s = 0.f;
        #pragma unroll
        for (int ks = 0; ks < 2; ++ks) {
            bq[nt][ks] = *(const bf16x8*)(qkvb +
                (size_t)(b * SEQ + nw + nt * 16 + lr) * 2304 + h * 64 + ks * 32 + lg * 8);
            #pragma unroll
            for (int j = 0; j < 8; ++j) {
                const float f = bf2f((unsigned short)bq[nt][ks][j]);
                s += f * f;
            }
        }
        s += __shfl_xor(s, 16);
        s += __shfl_xor(s, 32);
        sqn[nt] = s * HALF_SCALE2;
    }

    f32x4 acc[5][2] = {};
    const unsigned short* ktg = ktvT + (size_t)bh * 80 * MFEAT;

    for (int ch = 0; ch < 4; ++ch) {
        const int m0 = ch * 96;
        __syncthreads();
        for (int i = t; i < 1920; i += 256) {
            const int row = i / 24, q = i % 24;
            *(ushort4*)&KT[row][q * 4] =
                *(const ushort4*)(ktg + (size_t)row * MFEAT + m0 + q * 4);
        }
        __syncthreads();

        #pragma unroll
        for (int mt = 0; mt < 6; ++mt) {
            bf16x8 afw[2];
            #pragma unroll
            for (int ks = 0; ks < 2; ++ks)
                afw[ks] = *(const bf16x8*)(worf_ts +
                    (size_t)(h * MFEAT + m0 + mt * 16 + lr) * HDIM + ks * 32 + lg * 8);
            #pragma unroll
            for (int nt = 0; nt < 2; ++nt) {
                f32x4 p = {};
                p = __builtin_amdgcn_mfma_f32_16x16x32_bf16(afw[0], bq[nt][0], p, 0, 0, 0);
                p = __builtin_amdgcn_mfma_f32_16x16x32_bf16(afw[1], bq[nt][1], p, 0, 0, 0);
                ushort4 pk;
                pk.x = f2bf(__expf(p[0] - sqn[nt]));
                pk.y = f2bf(__expf(p[1] - sqn[nt]));
                pk.z = f2bf(__expf(p[2] - sqn[nt]));
                pk.w = f2bf(__expf(p[3] - sqn[nt]));
                *(ushort4*)&P[w][nt * 16 + lr][mt * 16 + lg * 4] = pk;
            }
        }
        asm volatile("s_waitcnt lgkmcnt(0)" ::: "memory");
        __builtin_amdgcn_sched_barrier(0);

        #pragma unroll
        for (int ks = 0; ks < 3; ++ks) {
            bf16x8 bp[2];
            #pragma unroll
            for (int nt = 0; nt < 2; ++nt)
                bp[nt] = *(const bf16x8*)&P[w][nt * 16 + lr][ks * 32 + lg * 8];
            #pragma unroll
            for (int ct = 0; ct < 5; ++ct) {
                const bf16x8 av = *(const bf16x8*)&KT[ct * 16 + lr][ks * 32 + lg * 8];
                #pragma unroll
                for (int nt = 0; nt < 2; ++nt)
                    acc[ct][nt] = __builtin_amdgcn_mfma_f32_16x16x32_bf16(av, bp[nt], acc[ct][nt], 0, 0, 0);
            }
        }
    }

    #pragma unroll
    for (int nt = 0; nt < 2; ++nt) {
        const float d = __shfl(acc[4][nt][0], lr);
        const float inv = 1.0f / (d + EPSP);
        const int token = b * SEQ + nw + nt * 16 + lr;
        #pragma unroll
        for (int ct = 0; ct < 4; ++ct)
            #pragma unroll
            for (int r = 0; r < 4; ++r) {
                const int cc = ct * 16 + lg * 4 + r;
                attn[(size_t)token * DIMD + h * 64 + cc] = f2bf(acc[ct][nt][r] * inv);
            }
    }
}

// ---------------------------------------------------------------------------
extern "C" void kernel_launch(void* const* d_in, const int* in_sizes, int n_in,
                              void* d_out, int out_size, void* d_ws, size_t ws_size,
                              hipStream_t stream) {
    const float* x      = (const float*)d_in[0];
    const float* ln1_g  = (const float*)d_in[1];
    const float* ln1_b  = (const float*)d_in[2];
    const float* qkv_w  = (const float*)d_in[3];
    const float* qkv_b  = (const float*)d_in[4];
    const float* w_orf  = (const float*)d_in[5];
    const float* proj_w = (const float*)d_in[6];
    const float* proj_b = (const float*)d_in[7];
    const float* ln2_g  = (const float*)d_in[8];
    const float* ln2_b  = (const float*)d_in[9];
    const float* fc1_w  = (const float*)d_in[10];
    const float* fc1_b  = (const float*)d_in[11];
    const float* fc2_w  = (const float*)d_in[12];
    const float* fc2_b  = (const float*)d_in[13];
    float* out = (float*)d_out;

    // Workspace layout (bytes), total 265,814,016 B (= round-3 proven size).
    char* wsb = (char*)d_ws;
    unsigned short* qkvb    = (unsigned short*)wsb;                  // bf16 T*2304 [0, 150994944)
    unsigned short* attn    = (unsigned short*)(wsb + 150994944);    // bf16 T*768  [.., 201326592)
    unsigned short* ktvT    = (unsigned short*)(wsb + 201326592);    // bf16 384*80*384 = 23,592,960
    unsigned short* worf_ts = (unsigned short*)(wsb + 224919552);    // bf16 12*384*64 = 589,824
    unsigned short* y2      = (unsigned short*)(wsb + 201326592);    // LN2 out (ktvT/worf_ts dead)
    unsigned short* hid     = qkvb;                                  // bf16 T*3072 aliases qkvb+attn
    unsigned short* qkv_wt  = (unsigned short*)(wsb + 251658240);    // [2304,768]  3,538,944
    unsigned short* proj_wt = (unsigned short*)(wsb + 255197184);    // [768,768]   1,179,648
    unsigned short* fc1_wt  = (unsigned short*)(wsb + 256376832);    // [3072,768]  4,718,592
    unsigned short* fc2_wt  = (unsigned short*)(wsb + 261095424);    // [768,3072]  4,718,592
    unsigned short* xln     = (unsigned short*)d_out;                // bf16 T*768 in d_out (free until step 5)

    // 0) weight prep
    wconv<<<dim3(2304 / 32, 768 / 32), 256, 0, stream>>>(qkv_w, qkv_wt, DIMD, 2304);
    wconv<<<dim3(768 / 32, 768 / 32), 256, 0, stream>>>(proj_w, proj_wt, DIMD, DIMD);
    wconv<<<dim3(3072 / 32, 768 / 32), 256, 0, stream>>>(fc1_w, fc1_wt, DIMD, HIDDEN);
    wconv<<<dim3(768 / 32, 3072 / 32), 256, 0, stream>>>(fc2_w, fc2_wt, HIDDEN, DIMD);
    wprep<<<dim3(MFEAT / 32, HDIM / 32, HEADS), 256, 0, stream>>>(w_orf, worf_ts);
    // 1) xln = LN1(x) (bf16, in d_out)
    ln_bf16<<<NTOK, 256, 0, stream>>>(x, ln1_g, ln1_b, xln);
    // 2) qkv = xln @ qkv_w + qkv_b (bf16)
    gemm_mfma<0, false, true><<<dim3(2304 / 128, NTOK / 256), 256, 0, stream>>>(
        xln, qkv_wt, qkv_b, nullptr, qkvb, DIMD, 2304);
    // 3) phase A: ktvT (incl. ksum row)
    ktv_mfma<<<dim3(HEADS, BATCH), 256, 0, stream>>>(qkvb, worf_ts, ktvT);
    // 4) phase B: attn out (bf16)
    attn_out_mfma<<<dim3(SEQ / 128, HEADS, BATCH), 256, 0, stream>>>(
        qkvb, worf_ts, ktvT, attn);
    // 5) h = x + attn @ proj_w + proj_b -> d_out (f32)
    gemm_mfma<0, true, false><<<dim3(DIMD / 128, NTOK / 256), 256, 0, stream>>>(
        attn, proj_wt, proj_b, x, out, DIMD, DIMD);
    // 6) y2 = LN2(h) (bf16)
    ln_bf16<<<NTOK, 256, 0, stream>>>(out, ln2_g, ln2_b, y2);
    // 7) hid = gelu(y2 @ fc1_w + fc1_b) (bf16)
    gemm_mfma<1, false, true><<<dim3(HIDDEN / 128, NTOK / 256), 256, 0, stream>>>(
        y2, fc1_wt, fc1_b, nullptr, hid, DIMD, HIDDEN);
    // 8) out = h + hid @ fc2_w + fc2_b (in-place residual on d_out)
    gemm_mfma<0, true, false><<<dim3(DIMD / 128, NTOK / 256), 256, 0, stream>>>(
        hid, fc2_wt, fc2_b, out, out, HIDDEN, DIMD);
}

// Round 9
// 953.594 us; speedup vs baseline: 1.1007x; 1.0346x over previous
//
#include <hip/hip_runtime.h>
#include <hip/hip_bf16.h>

// Problem constants
#define NTOK   32768          // 32 * 1024 tokens
#define BATCH  32
#define SEQ    1024
#define DIMD   768
#define HEADS  12
#define HDIM   64
#define MFEAT  384
#define HIDDEN 3072
#define SCALE  0.35355339059327379f   // 64^-0.25
#define HALF_SCALE2 0.0625f           // 0.5 * SCALE^2
#define EPSP   3.84e-6f               // 1e-8 / RSM^2 (RSM factors cancel in out)

typedef __attribute__((ext_vector_type(8))) short bf16x8;
typedef __attribute__((ext_vector_type(4))) float f32x4;

static __device__ __forceinline__ float bf2f(unsigned short u) {
    return __uint_as_float(((unsigned)u) << 16);
}
static __device__ __forceinline__ unsigned short f2bf(float f) {
    unsigned u = __float_as_uint(f);
    return (unsigned short)((u + 0x7FFFu + ((u >> 16) & 1u)) >> 16);  // RNE
}
// gelu tanh-approx, exp form: 0.5v(1+tanh(u)) == v / (1 + e^{-2u})
static __device__ __forceinline__ float gelu_fast(float v) {
    const float c = 0.7978845608028654f;
    const float u = c * v * (1.0f + 0.044715f * v * v);
    return v / (1.0f + __expf(-2.0f * u));
}
static __device__ __forceinline__ void gload16(const void* g, void* l) {
    __builtin_amdgcn_global_load_lds(
        (const __attribute__((address_space(1))) void*)g,
        (__attribute__((address_space(3))) void*)l, 16, 0, 0);
}

// ---------------- fused LayerNorm -> bf16 (one block per 768-elem row) -----
__global__ __launch_bounds__(256) void ln_bf16(
    const float* __restrict__ x, const float* __restrict__ g,
    const float* __restrict__ bta, unsigned short* __restrict__ o) {
    const size_t row = blockIdx.x;
    const float* xr = x + row * DIMD;
    unsigned short* orow = o + row * DIMD;
    const int t = threadIdx.x;
    const float v0 = xr[t], v1 = xr[t + 256], v2 = xr[t + 512];
    float s  = v0 + v1 + v2;
    float sq = v0 * v0 + v1 * v1 + v2 * v2;
    const int lane = t & 63, w = t >> 6;
    #pragma unroll
    for (int off = 32; off > 0; off >>= 1) {
        s  += __shfl_down(s, off, 64);
        sq += __shfl_down(sq, off, 64);
    }
    __shared__ float red[2][4];
    if (lane == 0) { red[0][w] = s; red[1][w] = sq; }
    __syncthreads();
    s  = red[0][0] + red[0][1] + red[0][2] + red[0][3];
    sq = red[1][0] + red[1][1] + red[1][2] + red[1][3];
    const float mu  = s * (1.0f / DIMD);
    const float var = sq * (1.0f / DIMD) - mu * mu;
    const float r = rsqrtf(var + 1e-5f);
    orow[t]       = f2bf((v0 - mu) * r * g[t]       + bta[t]);
    orow[t + 256] = f2bf((v1 - mu) * r * g[t + 256] + bta[t + 256]);
    orow[t + 512] = f2bf((v2 - mu) * r * g[t + 512] + bta[t + 512]);
}

// ---------------- weight convert + transpose: W[K,N] f32 -> Wt[N,K] bf16 ---
__global__ __launch_bounds__(256) void wconv(
    const float* __restrict__ W, unsigned short* __restrict__ Wt, int K, int N) {
    __shared__ float tile[32][33];
    const int n0 = blockIdx.x << 5, k0 = blockIdx.y << 5;
    const int tn = threadIdx.x & 31, tg = threadIdx.x >> 5;   // tg 0..7
    #pragma unroll
    for (int i = 0; i < 4; ++i) {
        const int k = (tg << 2) + i;
        tile[k][tn] = W[(size_t)(k0 + k) * N + n0 + tn];
    }
    __syncthreads();
    #pragma unroll
    for (int i = 0; i < 4; ++i) {
        const int n = (tg << 2) + i;
        Wt[(size_t)(n0 + n) * K + k0 + tn] = f2bf(tile[tn][n]);
    }
}

// ---------------- worf prep: worf_ts[h][m][c] = bf16(SCALE * worf[h][c][m])
__global__ __launch_bounds__(256) void wprep(
    const float* __restrict__ worf, unsigned short* __restrict__ worf_ts) {
    __shared__ float tile[32][33];
    const int m0 = blockIdx.x << 5, c0 = blockIdx.y << 5, h = blockIdx.z;
    const int tn = threadIdx.x & 31, tg = threadIdx.x >> 5;
    #pragma unroll
    for (int i = 0; i < 4; ++i) {
        const int c = (tg << 2) + i;
        tile[c][tn] = worf[(size_t)(h * HDIM + c0 + c) * MFEAT + m0 + tn];
    }
    __syncthreads();
    #pragma unroll
    for (int i = 0; i < 4; ++i) {
        const int m = (tg << 2) + i;
        worf_ts[(size_t)(h * MFEAT + m0 + m) * HDIM + c0 + tn] =
            f2bf(SCALE * tile[tn][m]);
    }
}

// ---------------- bf16 MFMA GEMM: C = A[M,K] @ Wt[N,K]^T + bias ------------
// 128x128 tile, BK=32, 4 waves (64x64 wave tile). TRIPLE-buffered LDS (48 KB
// -> 3 blocks/CU), depth-2 prefetch, counted vmcnt(4), ONE raw barrier/iter.
// LDS chunk swizzle (T2/rule-21): physical chunk = logical ^ ((row>>1)&3);
// gload_lds dest stays LINEAR, global SOURCE carries the inverse XOR, frag
// reads XOR the chunk index -> 8-way bank conflict becomes free 2-way.
// XCD-chunked grid swizzle (round-8 proven: FETCH 675->143 MB on fc2).
template <int ACT, bool RES, bool OBF16>
__global__ __launch_bounds__(256, 2) void gemm_mfma(
    const unsigned short* __restrict__ A, const unsigned short* __restrict__ Wt,
    const float* __restrict__ bias, const float* __restrict__ resid,
    void* __restrict__ Craw, int K, int N) {
    __shared__ unsigned short As[3][128 * 32];   // 8 KB per buffer
    __shared__ unsigned short Bs[3][128 * 32];
    const int t = threadIdx.x;
    const int w = t >> 6, l = t & 63;
    // XCD-chunked swizzle (all grids have nwg % 8 == 0)
    const int ncol = gridDim.x;
    const int lin = blockIdx.y * ncol + blockIdx.x;
    const int cpx = (ncol * gridDim.y) >> 3;
    const int wg = (lin & 7) * cpx + (lin >> 3);
    const int row0 = (wg / ncol) << 7, col0 = (wg % ncol) << 7;
    const int wr = (w >> 1) << 6, wc = (w & 1) << 6;

    // staging source: lane l -> row (l>>2) of its 16-row chunk, and the
    // 16B global chunk that belongs at physical slot (l&3) under the swizzle:
    // g = (l&3) ^ ((l>>3)&3)   [since (relrow>>1)&3 == (l>>3)&3]
    const int sc = (((l & 3) ^ ((l >> 3) & 3)) << 3);   // bf16 units
    const unsigned short* ag0 = A  + (size_t)(row0 + w * 32 + (l >> 2)) * K + sc;
    const unsigned short* ag1 = ag0 + (size_t)16 * K;
    const unsigned short* bg0 = Wt + (size_t)(col0 + w * 32 + (l >> 2)) * K + sc;
    const unsigned short* bg1 = bg0 + (size_t)16 * K;

    f32x4 acc[4][4] = {};
    const int NT = K >> 5;

    auto stage = [&](int bi, int s) {
        const size_t ko = (size_t)s << 5;   // 32 bf16 per K-step
        gload16(ag0 + ko, &As[bi][w * 1024]);
        gload16(ag1 + ko, &As[bi][w * 1024 + 512]);
        gload16(bg0 + ko, &Bs[bi][w * 1024]);
        gload16(bg1 + ko, &Bs[bi][w * 1024 + 512]);
    };

    stage(0, 0);
    stage(1, 1);
    const int lr = l & 15, lg = l >> 4;
    // frag read: logical chunk lg of row (..+lr) lives at physical chunk
    // lg ^ ((lr>>1)&3); lane-constant XOR term:
    const int lkx = (lg << 3) ^ ((((lr >> 1) & 3)) << 3);   // bf16 units
    int cur = 0;   // buffer holding tile s
    for (int s = 0; s < NT; ++s) {
        // wait for tile s's 4 loads; tile s+1's 4 stay in flight
        if (s + 1 < NT) asm volatile("s_waitcnt vmcnt(4)" ::: "memory");
        else            asm volatile("s_waitcnt vmcnt(0)" ::: "memory");
        __builtin_amdgcn_s_barrier();            // tile s in LDS; reads of buf (s+2)%3 done
        __builtin_amdgcn_sched_barrier(0);       // nothing hoists above the barrier
        if (s + 2 < NT) {
            int sb = cur + 2; if (sb >= 3) sb -= 3;
            stage(sb, s + 2);                    // ~2 iterations of flight time
        }
        const unsigned short* ab = &As[cur][0];
        const unsigned short* bb = &Bs[cur][0];
        bf16x8 af[4], bfr[4];
        #pragma unroll
        for (int f = 0; f < 4; ++f) {
            af[f]  = *(const bf16x8*)(ab + (wr + f * 16 + lr) * 32 + lkx);
            bfr[f] = *(const bf16x8*)(bb + (wc + f * 16 + lr) * 32 + lkx);
        }
        #pragma unroll
        for (int fi = 0; fi < 4; ++fi)
            #pragma unroll
            for (int fj = 0; fj < 4; ++fj)
                acc[fi][fj] = __builtin_amdgcn_mfma_f32_16x16x32_bf16(
                    af[fi], bfr[fj], acc[fi][fj], 0, 0, 0);
        cur = (cur + 1 == 3) ? 0 : cur + 1;
    }

    float bv[4];
    #pragma unroll
    for (int fj = 0; fj < 4; ++fj) bv[fj] = bias[col0 + wc + fj * 16 + lr];
    #pragma unroll
    for (int fi = 0; fi < 4; ++fi) {
        #pragma unroll
        for (int r = 0; r < 4; ++r) {
            const int row = row0 + wr + fi * 16 + lg * 4 + r;
            const size_t base = (size_t)row * N + col0 + wc + lr;
            #pragma unroll
            for (int fj = 0; fj < 4; ++fj) {
                float v = acc[fi][fj][r] + bv[fj];
                if constexpr (RES) v += resid[base + fj * 16];
                if constexpr (ACT == 1) v = gelu_fast(v);
                if constexpr (OBF16) ((unsigned short*)Craw)[base + fj * 16] = f2bf(v);
                else                 ((float*)Craw)[base + fj * 16] = v;
            }
        }
    }
}

// ---------------- Phase A (MFMA): per (b,h): ktvT[c][m] (+ksum row 64) -----
__global__ __launch_bounds__(256, 1) void ktv_mfma(
    const unsigned short* __restrict__ qkvb,
    const unsigned short* __restrict__ worf_ts,
    unsigned short* __restrict__ ktvT) {
    const int h = blockIdx.x, b = blockIdx.y, bh = b * HEADS + h;
    __shared__ __align__(16) unsigned short Klds[32][72];
    __shared__ __align__(16) unsigned short VT[80][40];
    __shared__ __align__(16) unsigned short P[4][96][40];
    const int t = threadIdx.x, w = t >> 6, l = t & 63;
    const int lr = l & 15, lg = l >> 4;
    const int m0 = w * 96;

    bf16x8 bfw[6][2];
    #pragma unroll
    for (int mt = 0; mt < 6; ++mt)
        #pragma unroll
        for (int ks = 0; ks < 2; ++ks)
            bfw[mt][ks] = *(const bf16x8*)(worf_ts +
                (size_t)(h * MFEAT + m0 + mt * 16 + lr) * HDIM + ks * 32 + lg * 8);

    f32x4 acc[5][6] = {};   // [c-tile][m-tile]

    for (int i = t; i < 16 * 40; i += 256) {
        const int r = 64 + i / 40, cc = i % 40;
        VT[r][cc] = (r == 64) ? (unsigned short)0x3F80 : (unsigned short)0;
    }
    const unsigned short* kglob = qkvb + (size_t)b * SEQ * 2304 + 768 + h * 64;
    const unsigned short* vglob = kglob + 768;

    for (int n0 = 0; n0 < SEQ; n0 += 32) {
        __syncthreads();
        {   // stage K tile [32][64]
            const int row = t >> 3, c8 = (t & 7) << 3;
            *(bf16x8*)&Klds[row][c8] =
                *(const bf16x8*)(kglob + (size_t)(n0 + row) * 2304 + c8);
        }
        {   // stage V^T tile [c][n]
            const int n = t & 31, c0 = (t >> 5) << 3;
            const unsigned short* src = vglob + (size_t)(n0 + n) * 2304 + c0;
            ushort4 v0 = *(const ushort4*)src;
            ushort4 v1 = *(const ushort4*)(src + 4);
            VT[c0 + 0][n] = v0.x; VT[c0 + 1][n] = v0.y;
            VT[c0 + 2][n] = v0.z; VT[c0 + 3][n] = v0.w;
            VT[c0 + 4][n] = v1.x; VT[c0 + 5][n] = v1.y;
            VT[c0 + 6][n] = v1.z; VT[c0 + 7][n] = v1.w;
        }
        __syncthreads();

        bf16x8 afk[2][2];
        float sqv[2][4];
        #pragma unroll
        for (int ns = 0; ns < 2; ++ns) {
            float s = 0.f;
            #pragma unroll
            for (int ks = 0; ks < 2; ++ks) {
                afk[ns][ks] = *(const bf16x8*)&Klds[ns * 16 + lr][ks * 32 + lg * 8];
                #pragma unroll
                for (int j = 0; j < 8; ++j) {
                    const float f = bf2f((unsigned short)afk[ns][ks][j]);
                    s += f * f;
                }
            }
            s += __shfl_xor(s, 16);
            s += __shfl_xor(s, 32);
            s *= HALF_SCALE2;
            #pragma unroll
            for (int r = 0; r < 4; ++r)
                sqv[ns][r] = __shfl(s, (lg << 2) + r);
        }

        #pragma unroll
        for (int mt = 0; mt < 6; ++mt) {
            #pragma unroll
            for (int ns = 0; ns < 2; ++ns) {
                f32x4 p = {};
                p = __builtin_amdgcn_mfma_f32_16x16x32_bf16(afk[ns][0], bfw[mt][0], p, 0, 0, 0);
                p = __builtin_amdgcn_mfma_f32_16x16x32_bf16(afk[ns][1], bfw[mt][1], p, 0, 0, 0);
                ushort4 pk;
                pk.x = f2bf(__expf(p[0] - sqv[ns][0]));
                pk.y = f2bf(__expf(p[1] - sqv[ns][1]));
                pk.z = f2bf(__expf(p[2] - sqv[ns][2]));
                pk.w = f2bf(__expf(p[3] - sqv[ns][3]));
                *(ushort4*)&P[w][mt * 16 + lr][ns * 16 + lg * 4] = pk;
            }
        }
        asm volatile("s_waitcnt lgkmcnt(0)" ::: "memory");
        __builtin_amdgcn_sched_barrier(0);

        bf16x8 afv[5];
        #pragma unroll
        for (int ct = 0; ct < 5; ++ct)
            afv[ct] = *(const bf16x8*)&VT[ct * 16 + lr][lg * 8];
        #pragma unroll
        for (int mt = 0; mt < 6; ++mt) {
            const bf16x8 bp = *(const bf16x8*)&P[w][mt * 16 + lr][lg * 8];
            #pragma unroll
            for (int ct = 0; ct < 5; ++ct)
                acc[ct][mt] = __builtin_amdgcn_mfma_f32_16x16x32_bf16(afv[ct], bp, acc[ct][mt], 0, 0, 0);
        }
    }

    unsigned short* dst = ktvT + (size_t)bh * 80 * MFEAT;
    #pragma unroll
    for (int ct = 0; ct < 5; ++ct)
        #pragma unroll
        for (int mt = 0; mt < 6; ++mt)
            #pragma unroll
            for (int r = 0; r < 4; ++r) {
                const int cc = ct * 16 + lg * 4 + r;
                const int m = m0 + mt * 16 + lr;
                dst[(size_t)cc * MFEAT + m] = f2bf(acc[ct][mt][r]);
            }
}

// ---------------- Phase B (MFMA): out^T[c,n] = sum_m ktvT[c,m] * phi_q[n,m]
__global__ __launch_bounds__(256) void attn_out_mfma(
    const unsigned short* __restrict__ qkvb,
    const unsigned short* __restrict__ worf_ts,
    const unsigned short* __restrict__ ktvT,
    unsigned short* __restrict__ attn) {
    const int n0 = blockIdx.x << 7;
    const int h = blockIdx.y, b = blockIdx.z, bh = b * HEADS + h;
    __shared__ __align__(16) unsigned short KT[80][104];
    __shared__ __align__(16) unsigned short P[4][32][104];
    const int t = threadIdx.x, w = t >> 6, l = t & 63;
    const int lr = l & 15, lg = l >> 4;
    const int nw = n0 + w * 32;

    bf16x8 bq[2][2];
    float sqn[2];
    #pragma unroll
    for (int nt = 0; nt < 2; ++nt) {
        float s = 0.f;
        #pragma unroll
        for (int ks = 0; ks < 2; ++ks) {
            bq[nt][ks] = *(const bf16x8*)(qkvb +
                (size_t)(b * SEQ + nw + nt * 16 + lr) * 2304 + h * 64 + ks * 32 + lg * 8);
            #pragma unroll
            for (int j = 0; j < 8; ++j) {
                const float f = bf2f((unsigned short)bq[nt][ks][j]);
                s += f * f;
            }
        }
        s += __shfl_xor(s, 16);
        s += __shfl_xor(s, 32);
        sqn[nt] = s * HALF_SCALE2;
    }

    f32x4 acc[5][2] = {};
    const unsigned short* ktg = ktvT + (size_t)bh * 80 * MFEAT;

    for (int ch = 0; ch < 4; ++ch) {
        const int m0 = ch * 96;
        __syncthreads();
        for (int i = t; i < 1920; i += 256) {
            const int row = i / 24, q = i % 24;
            *(ushort4*)&KT[row][q * 4] =
                *(const ushort4*)(ktg + (size_t)row * MFEAT + m0 + q * 4);
        }
        __syncthreads();

        #pragma unroll
        for (int mt = 0; mt < 6; ++mt) {
            bf16x8 afw[2];
            #pragma unroll
            for (int ks = 0; ks < 2; ++ks)
                afw[ks] = *(const bf16x8*)(worf_ts +
                    (size_t)(h * MFEAT + m0 + mt * 16 + lr) * HDIM + ks * 32 + lg * 8);
            #pragma unroll
            for (int nt = 0; nt < 2; ++nt) {
                f32x4 p = {};
                p = __builtin_amdgcn_mfma_f32_16x16x32_bf16(afw[0], bq[nt][0], p, 0, 0, 0);
                p = __builtin_amdgcn_mfma_f32_16x16x32_bf16(afw[1], bq[nt][1], p, 0, 0, 0);
                ushort4 pk;
                pk.x = f2bf(__expf(p[0] - sqn[nt]));
                pk.y = f2bf(__expf(p[1] - sqn[nt]));
                pk.z = f2bf(__expf(p[2] - sqn[nt]));
                pk.w = f2bf(__expf(p[3] - sqn[nt]));
                *(ushort4*)&P[w][nt * 16 + lr][mt * 16 + lg * 4] = pk;
            }
        }
        asm volatile("s_waitcnt lgkmcnt(0)" ::: "memory");
        __builtin_amdgcn_sched_barrier(0);

        #pragma unroll
        for (int ks = 0; ks < 3; ++ks) {
            bf16x8 bp[2];
            #pragma unroll
            for (int nt = 0; nt < 2; ++nt)
                bp[nt] = *(const bf16x8*)&P[w][nt * 16 + lr][ks * 32 + lg * 8];
            #pragma unroll
            for (int ct = 0; ct < 5; ++ct) {
                const bf16x8 av = *(const bf16x8*)&KT[ct * 16 + lr][ks * 32 + lg * 8];
                #pragma unroll
                for (int nt = 0; nt < 2; ++nt)
                    acc[ct][nt] = __builtin_amdgcn_mfma_f32_16x16x32_bf16(av, bp[nt], acc[ct][nt], 0, 0, 0);
            }
        }
    }

    #pragma unroll
    for (int nt = 0; nt < 2; ++nt) {
        const float d = __shfl(acc[4][nt][0], lr);
        const float inv = 1.0f / (d + EPSP);
        const int token = b * SEQ + nw + nt * 16 + lr;
        #pragma unroll
        for (int ct = 0; ct < 4; ++ct)
            #pragma unroll
            for (int r = 0; r < 4; ++r) {
                const int cc = ct * 16 + lg * 4 + r;
                attn[(size_t)token * DIMD + h * 64 + cc] = f2bf(acc[ct][nt][r] * inv);
            }
    }
}

// ---------------------------------------------------------------------------
extern "C" void kernel_launch(void* const* d_in, const int* in_sizes, int n_in,
                              void* d_out, int out_size, void* d_ws, size_t ws_size,
                              hipStream_t stream) {
    const float* x      = (const float*)d_in[0];
    const float* ln1_g  = (const float*)d_in[1];
    const float* ln1_b  = (const float*)d_in[2];
    const float* qkv_w  = (const float*)d_in[3];
    const float* qkv_b  = (const float*)d_in[4];
    const float* w_orf  = (const float*)d_in[5];
    const float* proj_w = (const float*)d_in[6];
    const float* proj_b = (const float*)d_in[7];
    const float* ln2_g  = (const float*)d_in[8];
    const float* ln2_b  = (const float*)d_in[9];
    const float* fc1_w  = (const float*)d_in[10];
    const float* fc1_b  = (const float*)d_in[11];
    const float* fc2_w  = (const float*)d_in[12];
    const float* fc2_b  = (const float*)d_in[13];
    float* out = (float*)d_out;

    // Workspace layout (bytes), total 265,814,016 B (= round-3 proven size).
    char* wsb = (char*)d_ws;
    unsigned short* qkvb    = (unsigned short*)wsb;                  // bf16 T*2304 [0, 150994944)
    unsigned short* attn    = (unsigned short*)(wsb + 150994944);    // bf16 T*768  [.., 201326592)
    unsigned short* ktvT    = (unsigned short*)(wsb + 201326592);    // bf16 384*80*384 = 23,592,960
    unsigned short* worf_ts = (unsigned short*)(wsb + 224919552);    // bf16 12*384*64 = 589,824
    unsigned short* y2      = (unsigned short*)(wsb + 201326592);    // LN2 out (ktvT/worf_ts dead)
    unsigned short* hid     = qkvb;                                  // bf16 T*3072 aliases qkvb+attn
    unsigned short* qkv_wt  = (unsigned short*)(wsb + 251658240);    // [2304,768]  3,538,944
    unsigned short* proj_wt = (unsigned short*)(wsb + 255197184);    // [768,768]   1,179,648
    unsigned short* fc1_wt  = (unsigned short*)(wsb + 256376832);    // [3072,768]  4,718,592
    unsigned short* fc2_wt  = (unsigned short*)(wsb + 261095424);    // [768,3072]  4,718,592
    unsigned short* xln     = (unsigned short*)d_out;                // bf16 T*768 in d_out (free until step 5)

    // 0) weight prep
    wconv<<<dim3(2304 / 32, 768 / 32), 256, 0, stream>>>(qkv_w, qkv_wt, DIMD, 2304);
    wconv<<<dim3(768 / 32, 768 / 32), 256, 0, stream>>>(proj_w, proj_wt, DIMD, DIMD);
    wconv<<<dim3(3072 / 32, 768 / 32), 256, 0, stream>>>(fc1_w, fc1_wt, DIMD, HIDDEN);
    wconv<<<dim3(768 / 32, 3072 / 32), 256, 0, stream>>>(fc2_w, fc2_wt, HIDDEN, DIMD);
    wprep<<<dim3(MFEAT / 32, HDIM / 32, HEADS), 256, 0, stream>>>(w_orf, worf_ts);
    // 1) xln = LN1(x) (bf16, in d_out)
    ln_bf16<<<NTOK, 256, 0, stream>>>(x, ln1_g, ln1_b, xln);
    // 2) qkv = xln @ qkv_w + qkv_b (bf16)
    gemm_mfma<0, false, true><<<dim3(2304 / 128, NTOK / 128), 256, 0, stream>>>(
        xln, qkv_wt, qkv_b, nullptr, qkvb, DIMD, 2304);
    // 3) phase A: ktvT (incl. ksum row)
    ktv_mfma<<<dim3(HEADS, BATCH), 256, 0, stream>>>(qkvb, worf_ts, ktvT);
    // 4) phase B: attn out (bf16)
    attn_out_mfma<<<dim3(SEQ / 128, HEADS, BATCH), 256, 0, stream>>>(
        qkvb, worf_ts, ktvT, attn);
    // 5) h = x + attn @ proj_w + proj_b -> d_out (f32)
    gemm_mfma<0, true, false><<<dim3(DIMD / 128, NTOK / 128), 256, 0, stream>>>(
        attn, proj_wt, proj_b, x, out, DIMD, DIMD);
    // 6) y2 = LN2(h) (bf16)
    ln_bf16<<<NTOK, 256, 0, stream>>>(out, ln2_g, ln2_b, y2);
    // 7) hid = gelu(y2 @ fc1_w + fc1_b) (bf16)
    gemm_mfma<1, false, true><<<dim3(HIDDEN / 128, NTOK / 128), 256, 0, stream>>>(
        y2, fc1_wt, fc1_b, nullptr, hid, DIMD, HIDDEN);
    // 8) out = h + hid @ fc2_w + fc2_b (in-place residual on d_out)
    gemm_mfma<0, true, false><<<dim3(DIMD / 128, NTOK / 128), 256, 0, stream>>>(
        hid, fc2_wt, fc2_b, out, out, HIDDEN, DIMD);
}